// Round 3
// baseline (5099.947 us; speedup 1.0000x reference)
//
#include <hip/hip_runtime.h>

typedef unsigned short u16;
typedef unsigned int u32;
typedef unsigned long long u64;
typedef short v8s __attribute__((ext_vector_type(8)));
typedef int v4i __attribute__((ext_vector_type(4)));
typedef float f32x4 __attribute__((ext_vector_type(4)));

#define NB 128
#define NU 1024
#define NF 64
#define NT 256
#define NOUT 32
#define NBLK 256
#define XS 72       // LDS X row stride in u16: 64 + 8 pad
#define FPAD 16     // u32 per barrier flag line (64 B) -> no write sharing

__device__ __forceinline__ u16 f2bf(float f) {
  union { float f; u32 u; } v; v.f = f;
  u32 x = v.u;
  return (u16)((x + 0x7fffu + ((x >> 16) & 1u)) >> 16);
}
__device__ __forceinline__ float bf2f(u16 u) {
  union { u32 u; float f; } v; v.u = ((u32)u) << 16;
  return v.f;
}

// --- coherent (agent-scope, fence-free) access helpers ---
__device__ __forceinline__ u64 cload64(const u16* p) {
  return __hip_atomic_load((const u64*)(const void*)p, __ATOMIC_RELAXED,
                           __HIP_MEMORY_SCOPE_AGENT);
}
__device__ __forceinline__ void cstore64(u16* p, u64 v) {
  __hip_atomic_store((u64*)(void*)p, v, __ATOMIC_RELAXED, __HIP_MEMORY_SCOPE_AGENT);
}
__device__ __forceinline__ float cloadf(const float* p) {
  return __hip_atomic_load(p, __ATOMIC_RELAXED, __HIP_MEMORY_SCOPE_AGENT);
}
__device__ __forceinline__ void cstoref(float* p, float v) {
  __hip_atomic_store(p, v, __ATOMIC_RELAXED, __HIP_MEMORY_SCOPE_AGENT);
}
// 16B coherent load: sc0 sc1 reads at the coherence point.
// Result valid only after an explicit s_waitcnt vmcnt(0).
__device__ __forceinline__ v4i cload128(const void* p) {
  v4i r;
  asm volatile("global_load_dwordx4 %0, %1, off sc0 sc1" : "=v"(r) : "v"(p) : "memory");
  return r;
}

// Per-GROUP barrier (64 blocks sharing one mg batch-group; groups are fully
// decoupled). Flags padded to 64B (single writer per line). Wave 0 of every
// block polls the group's 64 flags directly (lane l -> flag l): 2 serialized
// hops, 64 readers/line, no cross-group jitter accumulation.
__device__ __forceinline__ void gbar(u32* arr, u32 gen, int grp, int bid, int tid) {
  asm volatile("s_waitcnt vmcnt(0)" ::: "memory");
  __syncthreads();
  if (tid == 0)
    __hip_atomic_store(&arr[bid * FPAD], gen, __ATOMIC_RELAXED, __HIP_MEMORY_SCOPE_AGENT);
  if (tid < 64) {
    const u32* fl = arr + (grp * 64 + tid) * FPAD;
    bool ok = false;
    u32 spin = 0;
    for (;;) {
      if (!ok)
        ok = __hip_atomic_load(fl, __ATOMIC_RELAXED, __HIP_MEMORY_SCOPE_AGENT) >= gen;
      if (__all(ok)) break;
      if (++spin > 50000000u) break;  // escape hatch
    }
  }
  __syncthreads();
  asm volatile("" ::: "memory");
}

__global__ void init_bar(u32* bar) {
  int i = blockIdx.x * 256 + threadIdx.x;
  if (i < 16384) bar[i] = 0;
}

// Pack [top(ktop x 4096); R(1024 x 4096)] into MFMA-B-fragment-major bf16 with
// gate-permuted columns: z' col (t*16 + q*4 + c) <- orig col (q*1024 + t*4 + c).
__global__ void pack_weights(const float* __restrict__ top, const float* __restrict__ R,
                             int ktop, int nchunk, u16* __restrict__ dst) {
  int line = blockIdx.x * 256 + threadIdx.x;
  int l = line & 63;
  int rest = line >> 6;
  int s = rest & 1; rest >>= 1;
  int kk = rest % nchunk;
  int t  = rest / nchunk;
  if (t >= 256) return;
  int kbase = kk * 64 + s * 32 + (l >> 4) * 8;
  int col = ((l >> 2) & 3) * 1024 + t * 4 + (l & 3);
  v8s o;
#pragma unroll
  for (int j = 0; j < 8; ++j) {
    int k = kbase + j;
    float v = (k < ktop) ? top[(size_t)k * 4096 + col]
                         : R[(size_t)(k - ktop) * 4096 + col];
    o[j] = (short)f2bf(v);
  }
  *(v8s*)(void*)(dst + (size_t)line * 8) = o;
}

struct P {
  const float* x;
  const u16 *packE, *packC, *packR;
  const float *bl, *bc, *br, *W1, *b1, *W2, *b2;
  u16 *h0, *h1, *hl0, *hl1, *hr0, *hr1;
  float* pred;   // fp32, coherent
  float* out;
  u32* bar;
};

// ---- Asb layout: [32 rows][2048 u16], row stride 4096 B (16B-aligned).
// XOR swizzle on 16B units: phys_unit = unit ^ (row & 7). Bijective within
// each 128B octet; makes both staged writes and MFMA fragment reads spread
// over all 32 banks (T2-style conflict-free).
__device__ __forceinline__ v8s ldA(const u16* Asb, int row, int unit) {
  return *(const v8s*)(const void*)(Asb + row * 2048 + ((unit ^ (row & 7)) * 8));
}

// stage 32 rows x 1024 u16 into units [dstu, dstu+128), 16 loads in flight.
__device__ __forceinline__ void stageH(u16* Asb, int tid, int m0,
                                       const u16* src, int dstu) {
  v4i t[16];
#pragma unroll
  for (int i = 0; i < 16; ++i) {
    int idx = tid + i * 256;
    int r = idx >> 7, ln = idx & 127;
    t[i] = cload128(src + (size_t)(m0 + r) * NU + ln * 8);
  }
  asm volatile("s_waitcnt vmcnt(0)" ::: "memory");
#pragma unroll
  for (int i = 0; i < 16; ++i) {
    int idx = tid + i * 256;
    int r = idx >> 7, ln = idx & 127;
    int u = (dstu + ln) ^ (r & 7);
    *(v4i*)(void*)(Asb + r * 2048 + u * 8) = t[i];
  }
}

// two tiles staged with ONE exposed latency: 32 loads in flight.
__device__ __forceinline__ void stageH2(u16* Asb, int tid, int m0,
                                        const u16* s0, const u16* s1) {
  v4i a[16], b[16];
#pragma unroll
  for (int i = 0; i < 16; ++i) {
    int idx = tid + i * 256;
    int r = idx >> 7, ln = idx & 127;
    a[i] = cload128(s0 + (size_t)(m0 + r) * NU + ln * 8);
  }
#pragma unroll
  for (int i = 0; i < 16; ++i) {
    int idx = tid + i * 256;
    int r = idx >> 7, ln = idx & 127;
    b[i] = cload128(s1 + (size_t)(m0 + r) * NU + ln * 8);
  }
  asm volatile("s_waitcnt vmcnt(0)" ::: "memory");
#pragma unroll
  for (int i = 0; i < 16; ++i) {
    int idx = tid + i * 256;
    int r = idx >> 7, ln = idx & 127;
    int u = ln ^ (r & 7);
    *(v4i*)(void*)(Asb + r * 2048 + u * 8) = a[i];
  }
#pragma unroll
  for (int i = 0; i < 16; ++i) {
    int idx = tid + i * 256;
    int r = idx >> 7, ln = idx & 127;
    int u = (128 + ln) ^ (r & 7);
    *(v4i*)(void*)(Asb + r * 2048 + u * 8) = b[i];
  }
}

// x(t) -> Xsb (plain loads: x is constant input)
__device__ __forceinline__ void stageX(u16* Xsb, int tid, int m0,
                                       const float* x, int t) {
#pragma unroll
  for (int i = 0; i < 4; ++i) {
    int idx = tid + i * 256;
    int ml = idx >> 5, dw = idx & 31;
    const float* sp = x + ((size_t)(m0 + ml) * NT + t) * NF + dw * 2;
    u32 v = (u32)f2bf(sp[0]) | ((u32)f2bf(sp[1]) << 16);
    *(u32*)(void*)(Xsb + ml * XS + dw * 2) = v;
  }
}

// pred -> Xsb (coherent loads: written by dense blocks of the same group)
__device__ __forceinline__ void stageP(u16* Xsb, int tid, int m0,
                                       const float* predf) {
#pragma unroll
  for (int i = 0; i < 4; ++i) {
    int idx = tid + i * 256;
    int ml = idx >> 5, dw = idx & 31;
    const float* sp = predf + (size_t)(m0 + ml) * NF + dw * 2;
    float f0 = cloadf(sp);
    float f1 = cloadf(sp + 1);
    u32 v = (u32)f2bf(f0) | ((u32)f2bf(f1) << 16);
    *(u32*)(void*)(Xsb + ml * XS + dw * 2) = v;
  }
}

__device__ __forceinline__ v8s afragEC(const u16* Asb, const u16* Xsb,
                                       int c, int row, int quad) {
  if (c < 2)
    return *(const v8s*)(const void*)(Xsb + row * XS + c * 32 + quad * 8);
  return ldA(Asb, row, (c - 2) * 4 + quad);
}

// x-only phase (t == 0): chunks 0..1 from Xsb.
__device__ __forceinline__ void mfmaX(f32x4& acc0, f32x4& acc1, const u16* Xsb,
                                      const u16* tb, int l15, int quad, int lane) {
#pragma unroll
  for (int j = 0; j < 2; ++j) {
    v8s b  = *(const v8s*)(const void*)(tb + ((size_t)(j * 64 + lane)) * 8);
    v8s a0 = *(const v8s*)(const void*)(Xsb + l15 * XS + j * 32 + quad * 8);
    v8s a1 = *(const v8s*)(const void*)(Xsb + (16 + l15) * XS + j * 32 + quad * 8);
    acc0 = __builtin_amdgcn_mfma_f32_16x16x32_bf16(a0, b, acc0, 0, 0, 0);
    acc1 = __builtin_amdgcn_mfma_f32_16x16x32_bf16(a1, b, acc1, 0, 0, 0);
  }
}

// Encoder/cellC: 34 chunks (0..1 = x/pred from Xsb, 2..33 = h from Asb), four
// independent accumulator chains to hide MFMA dep latency at 1 wave/SIMD.
__device__ __forceinline__ void mfmaEC(f32x4& x0, f32x4& x1, f32x4& y0, f32x4& y1,
                                       const u16* Asb, const u16* Xsb, const u16* tb,
                                       int l15, int quad, int lane) {
#pragma unroll
  for (int j = 0; j < 17; ++j) {
    const int ja = j, jb = 17 + j;
    v8s ba  = *(const v8s*)(const void*)(tb + ((size_t)(ja * 64 + lane)) * 8);
    v8s aa0 = afragEC(Asb, Xsb, ja, l15, quad);
    v8s aa1 = afragEC(Asb, Xsb, ja, 16 + l15, quad);
    v8s bb  = *(const v8s*)(const void*)(tb + ((size_t)(jb * 64 + lane)) * 8);
    v8s ab0 = afragEC(Asb, Xsb, jb, l15, quad);
    v8s ab1 = afragEC(Asb, Xsb, jb, 16 + l15, quad);
    x0 = __builtin_amdgcn_mfma_f32_16x16x32_bf16(aa0, ba, x0, 0, 0, 0);
    y0 = __builtin_amdgcn_mfma_f32_16x16x32_bf16(ab0, bb, y0, 0, 0, 0);
    x1 = __builtin_amdgcn_mfma_f32_16x16x32_bf16(aa1, ba, x1, 0, 0, 0);
    y1 = __builtin_amdgcn_mfma_f32_16x16x32_bf16(ab1, bb, y1, 0, 0, 0);
  }
}

// cellR: 64 chunks all from Asb (units 0..255).
__device__ __forceinline__ void mfmaR(f32x4& x0, f32x4& x1, f32x4& y0, f32x4& y1,
                                      const u16* Asb, const u16* tb,
                                      int l15, int quad, int lane) {
#pragma unroll
  for (int j = 0; j < 32; ++j) {
    const int ja = j, jb = 32 + j;
    v8s ba  = *(const v8s*)(const void*)(tb + ((size_t)(ja * 64 + lane)) * 8);
    v8s aa0 = ldA(Asb, l15, ja * 4 + quad);
    v8s aa1 = ldA(Asb, 16 + l15, ja * 4 + quad);
    v8s bb  = *(const v8s*)(const void*)(tb + ((size_t)(jb * 64 + lane)) * 8);
    v8s ab0 = ldA(Asb, l15, jb * 4 + quad);
    v8s ab1 = ldA(Asb, 16 + l15, jb * 4 + quad);
    x0 = __builtin_amdgcn_mfma_f32_16x16x32_bf16(aa0, ba, x0, 0, 0, 0);
    y0 = __builtin_amdgcn_mfma_f32_16x16x32_bf16(ab0, bb, y0, 0, 0, 0);
    x1 = __builtin_amdgcn_mfma_f32_16x16x32_bf16(aa1, ba, x1, 0, 0, 0);
    y1 = __builtin_amdgcn_mfma_f32_16x16x32_bf16(ab1, bb, y1, 0, 0, 0);
  }
}

// gates tail: z -> LDS transpose -> sigmoid/tanh. c-state lives in 2 registers
// per thread (block-private, fixed thread<->(m,col) mapping every step).
// h packed to 8B in LDS, stored coherent.
__device__ __forceinline__ void gates_store(float* zbuf, u16* hpk,
                                            int w, int lane, int quad, int l15,
                                            int m0, int tblk,
                                            const f32x4& acc0, const f32x4& acc1,
                                            const float* bias,
                                            float cpair[2], u16* hout, bool czero) {
#pragma unroll
  for (int r = 0; r < 4; ++r) {
    zbuf[(w * 32 + quad * 4 + r) * 17 + l15]      = acc0[r];
    zbuf[(w * 32 + 16 + quad * 4 + r) * 17 + l15] = acc1[r];
  }
  __syncthreads();
#pragma unroll
  for (int rep = 0; rep < 2; ++rep) {
    int pp = lane + rep * 64;
    int ml = pp >> 2;
    int cc = pp & 3;
    int col = tblk * 4 + cc;
    int zr = (w * 32 + ml) * 17;
    float iv = zbuf[zr + 0 + cc]  + bias[col];
    float fv = zbuf[zr + 4 + cc]  + bias[1024 + col];
    float gv = zbuf[zr + 8 + cc]  + bias[2048 + col];
    float ov = zbuf[zr + 12 + cc] + bias[3072 + col];
    float cold = czero ? 0.f : cpair[rep];
    float si = 1.f / (1.f + __expf(-iv));
    float sf = 1.f / (1.f + __expf(-fv));
    float so = 1.f / (1.f + __expf(-ov));
    float e2g = __expf(2.f * gv);
    float tg  = (e2g - 1.f) / (e2g + 1.f);
    float cn  = sf * cold + si * tg;
    float e2c = __expf(2.f * cn);
    float tc  = (e2c - 1.f) / (e2c + 1.f);
    cpair[rep] = cn;
    hpk[w * 128 + ml * 4 + cc] = f2bf(so * tc);
  }
  __syncthreads();
  if (lane < 32) {
    union { u16 h4[4]; u64 q; } u;
#pragma unroll
    for (int c = 0; c < 4; ++c) u.h4[c] = hpk[w * 128 + lane * 4 + c];
    cstore64(hout + (size_t)(m0 + lane) * NU + tblk * 4, u.q);
  }
}

// dense head, INTRA-GROUP: block wgn r < 32 of group mg owns batch row m0+r,
// so all dense producers/consumers stay inside the 64-block group.
__device__ void denseF(const P& p, float* dloc, int tid, int wgn, int m0,
                       const u16* hsrc, int step) {
  if (wgn < 32) {
    int m = m0 + wgn;
    int j = tid >> 3, sub = tid & 7;
    float sum = 0.f;
    const u16* hr = hsrc + (size_t)m * NU + sub * 128;
#pragma unroll
    for (int i = 0; i < 16; ++i) {
      u64 a = cload64(hr + i * 8);
      u64 b = cload64(hr + i * 8 + 4);
      union { u64 q[2]; u16 h[8]; } u; u.q[0] = a; u.q[1] = b;
#pragma unroll
      for (int e = 0; e < 8; ++e)
        sum += bf2f(u.h[e]) * p.W1[(sub * 128 + i * 8 + e) * 32 + j];
    }
    sum += __shfl_down(sum, 4, 8);
    sum += __shfl_down(sum, 2, 8);
    sum += __shfl_down(sum, 1, 8);
    if (sub == 0) dloc[j] = fmaxf(sum + p.b1[j], 0.f);
    __syncthreads();
    if (tid < 64) {
      int f = tid;
      float s2 = p.b2[f];
#pragma unroll
      for (int k = 0; k < 32; ++k) s2 += dloc[k] * p.W2[k * 64 + f];
      p.out[((size_t)m * NOUT + step) * NF + f] = s2;
      cstoref(&p.pred[(size_t)m * NF + f], s2);
    }
  }
}

__global__ void __launch_bounds__(256, 1) rnn_persist(P p) {
  __shared__ __align__(16) u16 Asb[32 * 2048];  // 131,072 B
  __shared__ __align__(16) u16 Xsb[32 * XS];    //   4,608 B
  __shared__ float zbuf[128 * 17];              //   8,704 B
  __shared__ u16 hpack[4 * 32 * 4];             //   1,024 B
  __shared__ float dloc[32];

  const int tid = threadIdx.x;
  const int bid = blockIdx.x;
  const int wgn = bid & 63;
  const int mg  = bid >> 6;    // group id: 4 independent groups of 64 blocks
  const int m0  = mg * 32;
  const int w    = tid >> 6;
  const int lane = tid & 63;
  const int quad = lane >> 4;
  const int l15  = lane & 15;
  const int tblk = wgn * 4 + w;

  const u16* tbE = p.packE + (size_t)tblk * 17408;  // [x(2 chunks); h(32 chunks)]
  const u16* tbC = p.packC + (size_t)tblk * 17408;  // [pred(2); hl(32)]
  const u16* tbR = p.packR + (size_t)tblk * 32768;  // [hl(32); hr(32)]

  float cE2[2] = {0.f, 0.f};  // encoder c-state, in registers
  u32 bno = 0;

  // ---- encoder: 256 steps ----
  stageX(Xsb, tid, m0, p.x, 0);  // x(0) prefetch
  for (int t = 0; t < NT; ++t) {
    const u16* hread = (t & 1) ? p.h1 : p.h0;
    u16* hwrite      = (t & 1) ? p.h0 : p.h1;
    f32x4 x0 = {0.f, 0.f, 0.f, 0.f}, x1 = x0, y0 = x0, y1 = x0;
    if (t > 0) {
      stageH(Asb, tid, m0, hread, 0);
      __syncthreads();
      mfmaEC(x0, x1, y0, y1, Asb, Xsb, tbE, l15, quad, lane);
      x0 += y0; x1 += y1;
    } else {
      __syncthreads();  // covers pre-loop stageX
      mfmaX(x0, x1, Xsb, tbE, l15, quad, lane);
    }
    gates_store(zbuf, hpack, w, lane, quad, l15, m0, tblk, x0, x1,
                p.bl, cE2, hwrite, t == 0);
    if (t + 1 < NT) stageX(Xsb, tid, m0, p.x, t + 1);  // prefetch across barrier
    ++bno; gbar(p.bar, bno, mg, bid, tid);
  }
  // final encoder h in p.h0

  denseF(p, dloc, tid, wgn, m0, p.h0, 0);
  ++bno; gbar(p.bar, bno, mg, bid, tid);

  // ---- autoregressive: 31 steps ----
  float cL2[2] = {cE2[0], cE2[1]};  // state_lstm c init = encoder final c
  float cR2[2] = {cE2[0], cE2[1]};  // state_rnn  c init = encoder final c
  for (int s = 1; s < NOUT; ++s) {
    const u16* hlr = (s == 1) ? p.h0 : ((s & 1) ? p.hl1 : p.hl0);
    u16*       hlw = (s & 1) ? p.hl0 : p.hl1;
    const u16* hrr = (s == 1) ? p.h0 : ((s & 1) ? p.hr1 : p.hr0);
    u16*       hrw = (s & 1) ? p.hr0 : p.hr1;

    // lstm_cell: [pred(2 chunks, Xsb) | hl(32 chunks, Asb)]
    {
      f32x4 x0 = {0.f, 0.f, 0.f, 0.f}, x1 = x0, y0 = x0, y1 = x0;
      stageP(Xsb, tid, m0, p.pred);
      stageH(Asb, tid, m0, hlr, 0);
      __syncthreads();
      mfmaEC(x0, x1, y0, y1, Asb, Xsb, tbC, l15, quad, lane);
      x0 += y0; x1 += y1;
      gates_store(zbuf, hpack, w, lane, quad, l15, m0, tblk, x0, x1,
                  p.bc, cL2, hlw, false);
    }
    ++bno; gbar(p.bar, bno, mg, bid, tid);

    // rnn_cell: [hl_new | hr_old] staged with one exposed latency
    {
      f32x4 x0 = {0.f, 0.f, 0.f, 0.f}, x1 = x0, y0 = x0, y1 = x0;
      stageH2(Asb, tid, m0, hlw, hrr);
      __syncthreads();
      mfmaR(x0, x1, y0, y1, Asb, tbR, l15, quad, lane);
      x0 += y0; x1 += y1;
      gates_store(zbuf, hpack, w, lane, quad, l15, m0, tblk, x0, x1,
                  p.br, cR2, hrw, false);
    }
    ++bno; gbar(p.bar, bno, mg, bid, tid);

    denseF(p, dloc, tid, wgn, m0, hrw, s);
    ++bno; gbar(p.bar, bno, mg, bid, tid);
  }
}

extern "C" void kernel_launch(void* const* d_in, const int* in_sizes, int n_in,
                              void* d_out, int out_size, void* d_ws, size_t ws_size,
                              hipStream_t stream) {
  const float* x  = (const float*)d_in[0];
  const float* Wl = (const float*)d_in[1];
  const float* Rl = (const float*)d_in[2];
  const float* bl = (const float*)d_in[3];
  const float* Wc = (const float*)d_in[4];
  const float* Rc = (const float*)d_in[5];
  const float* bc = (const float*)d_in[6];
  const float* Wr = (const float*)d_in[7];
  const float* Rr = (const float*)d_in[8];
  const float* br = (const float*)d_in[9];
  const float* W1 = (const float*)d_in[10];
  const float* b1 = (const float*)d_in[11];
  const float* W2 = (const float*)d_in[12];
  const float* b2 = (const float*)d_in[13];

  char* ws = (char*)d_ws;
  size_t off = 0;
  auto alloc = [&](size_t bytes) -> void* {
    void* r = ws + off;
    off += (bytes + 255) & ~(size_t)255;
    return r;
  };
  const size_t szPackE = (size_t)256 * 17408 * 2;  // 8,912,896
  const size_t szPackR = (size_t)256 * 32768 * 2;  // 16,777,216
  u16* packE = (u16*)alloc(szPackE);
  u16* packC = (u16*)alloc(szPackE);
  u16* packR = (u16*)alloc(szPackR);
  u16* h0  = (u16*)alloc(NB * NU * 2);
  u16* h1  = (u16*)alloc(NB * NU * 2);
  u16* hl0 = (u16*)alloc(NB * NU * 2);
  u16* hl1 = (u16*)alloc(NB * NU * 2);
  u16* hr0 = (u16*)alloc(NB * NU * 2);
  u16* hr1 = (u16*)alloc(NB * NU * 2);
  float* pred = (float*)alloc(NB * NF * 4);
  u32* bar  = (u32*)alloc(16384 * 4);

  init_bar<<<dim3(64), dim3(256), 0, stream>>>(bar);
  pack_weights<<<dim3(128 * 17), dim3(256), 0, stream>>>(Wl, Rl, 64, 17, packE);
  pack_weights<<<dim3(128 * 17), dim3(256), 0, stream>>>(Wc, Rc, 64, 17, packC);
  pack_weights<<<dim3(128 * 32), dim3(256), 0, stream>>>(Wr, Rr, 1024, 32, packR);

  static P p;
  p.x = x;
  p.packE = packE; p.packC = packC; p.packR = packR;
  p.bl = bl; p.bc = bc; p.br = br;
  p.W1 = W1; p.b1 = b1; p.W2 = W2; p.b2 = b2;
  p.h0 = h0; p.h1 = h1; p.hl0 = hl0; p.hl1 = hl1; p.hr0 = hr0; p.hr1 = hr1;
  p.pred = pred;
  p.out = (float*)d_out;
  p.bar = bar;

  rnn_persist<<<dim3(NBLK), dim3(256), 0, stream>>>(p);
}

// Round 4
// 4273.973 us; speedup vs baseline: 1.1933x; 1.1933x over previous
//
#include <hip/hip_runtime.h>

typedef unsigned short u16;
typedef unsigned int u32;
typedef unsigned long long u64;
typedef short v8s __attribute__((ext_vector_type(8)));
typedef int v4i __attribute__((ext_vector_type(4)));
typedef float f32x4 __attribute__((ext_vector_type(4)));

#define NB 128
#define NU 1024
#define NF 64
#define NT 256
#define NOUT 32
#define NBLK 256
#define XS 72       // LDS X row stride in u16: 64 + 8 pad
#define FPAD 32     // u32 per barrier flag line (128 B) -> private MALL line
#define GO_OFF (NBLK * FPAD)

__device__ __forceinline__ u16 f2bf(float f) {
  union { float f; u32 u; } v; v.f = f;
  u32 x = v.u;
  return (u16)((x + 0x7fffu + ((x >> 16) & 1u)) >> 16);
}
__device__ __forceinline__ float bf2f(u16 u) {
  union { u32 u; float f; } v; v.u = ((u32)u) << 16;
  return v.f;
}

// --- coherent (agent-scope, fence-free) access helpers ---
__device__ __forceinline__ void cstore64(u16* p, u64 v) {
  __hip_atomic_store((u64*)(void*)p, v, __ATOMIC_RELAXED, __HIP_MEMORY_SCOPE_AGENT);
}
// 16B coherent load: sc0 sc1 reads at the coherence point.
// Result valid only after an explicit s_waitcnt vmcnt(0).
__device__ __forceinline__ v4i cload128(const void* p) {
  v4i r;
  asm volatile("global_load_dwordx4 %0, %1, off sc0 sc1" : "=v"(r) : "v"(p) : "memory");
  return r;
}

// Hierarchical per-group barrier, traffic-minimized:
//  - arrival: tid0 stores a private 128B line.
//  - leader block (wgn==0): wave0 lane l polls arrival line l (stops loading
//    once seen; s_sleep throttle), then lane l stores go-line of block l.
//  - others: tid0 polls its own private go-line (s_sleep throttle).
// 3 serialized MALL hops; poll traffic ~64+63 lines per group per iteration
// (vs 64*64 lines flat-polling in r3, which saturated MALL at ~1.5 KB/cy).
__device__ __forceinline__ void gbar(u32* bar, u32 gen, int grp, int wgn, int tid) {
  asm volatile("s_waitcnt vmcnt(0)" ::: "memory");
  __syncthreads();
  const int bid = grp * 64 + wgn;
  if (tid == 0)
    __hip_atomic_store(&bar[bid * FPAD], gen, __ATOMIC_RELAXED, __HIP_MEMORY_SCOPE_AGENT);
  u32* go = bar + GO_OFF;
  if (wgn == 0) {
    if (tid < 64) {
      const u32* fl = bar + (size_t)(grp * 64 + tid) * FPAD;
      bool ok = false;
      u32 spin = 0;
      for (;;) {
        if (!ok)
          ok = __hip_atomic_load(fl, __ATOMIC_RELAXED, __HIP_MEMORY_SCOPE_AGENT) >= gen;
        if (__all(ok)) break;
        __builtin_amdgcn_s_sleep(2);
        if (++spin > 2000000u) break;  // escape hatch
      }
      __hip_atomic_store(&go[(grp * 64 + tid) * FPAD], gen, __ATOMIC_RELAXED,
                         __HIP_MEMORY_SCOPE_AGENT);
    }
  } else if (tid == 0) {
    const u32* fl = go + (size_t)bid * FPAD;
    u32 spin = 0;
    while (__hip_atomic_load(fl, __ATOMIC_RELAXED, __HIP_MEMORY_SCOPE_AGENT) < gen) {
      __builtin_amdgcn_s_sleep(2);
      if (++spin > 2000000u) break;  // escape hatch
    }
  }
  __syncthreads();
  asm volatile("" ::: "memory");
}

__global__ void init_bar(u32* bar) {
  int i = blockIdx.x * 256 + threadIdx.x;
  if (i < 2 * NBLK * FPAD) bar[i] = 0;
}

// Pack [top(ktop x 4096); R(1024 x 4096)] into MFMA-B-fragment-major bf16 with
// gate-permuted columns: z' col (t*16 + q*4 + c) <- orig col (q*1024 + t*4 + c).
__global__ void pack_weights(const float* __restrict__ top, const float* __restrict__ R,
                             int ktop, int nchunk, u16* __restrict__ dst) {
  int line = blockIdx.x * 256 + threadIdx.x;
  int l = line & 63;
  int rest = line >> 6;
  int s = rest & 1; rest >>= 1;
  int kk = rest % nchunk;
  int t  = rest / nchunk;
  if (t >= 256) return;
  int kbase = kk * 64 + s * 32 + (l >> 4) * 8;
  int col = ((l >> 2) & 3) * 1024 + t * 4 + (l & 3);
  v8s o;
#pragma unroll
  for (int j = 0; j < 8; ++j) {
    int k = kbase + j;
    float v = (k < ktop) ? top[(size_t)k * 4096 + col]
                         : R[(size_t)(k - ktop) * 4096 + col];
    o[j] = (short)f2bf(v);
  }
  *(v8s*)(void*)(dst + (size_t)line * 8) = o;
}

// Pack W1 (1024 x 32 fp32) as bf16 hi (lines 0..63) + bf16 residual lo
// (lines 64..127), fragment-major: line = res*64 + c*2 + nt; lane l elem j
// <- W1[c*32 + (l>>4)*8 + j][nt*16 + (l&15)].  hi+lo makes the MFMA dense
// head numerically ~fp32 in W1.
__global__ void pack_w1(const float* __restrict__ W1, u16* __restrict__ dst) {
  int id = blockIdx.x * 256 + threadIdx.x;  // 8192 work items
  int lane = id & 63;
  int line = id >> 6;      // 0..127
  int res = line >> 6;     // 0=hi, 1=lo
  int cl = line & 63;
  int c = cl >> 1, nt = cl & 1;
  int krow = c * 32 + ((lane >> 4) * 8);
  int col = nt * 16 + (lane & 15);
  v8s o;
#pragma unroll
  for (int j = 0; j < 8; ++j) {
    float v = W1[(size_t)(krow + j) * 32 + col];
    u16 hi = f2bf(v);
    o[j] = (short)(res ? f2bf(v - bf2f(hi)) : hi);
  }
  *(v8s*)(void*)(dst + (size_t)id * 8) = o;
}

struct P {
  const float* x;
  const u16 *packE, *packC, *packR, *W1f;
  const float *bl, *bc, *br, *b1, *W2, *b2;
  u16 *h0, *h1, *hl0, *hl1, *hr0, *hr1;
  float* out;
  u32* bar;
};

// ---- Asb layout: [32 rows][2048 u16], row stride 4096 B. XOR swizzle on 16B
// units: phys_unit = unit ^ (row & 7).
__device__ __forceinline__ v8s ldA(const u16* Asb, int row, int unit) {
  return *(const v8s*)(const void*)(Asb + row * 2048 + ((unit ^ (row & 7)) * 8));
}

// stage 32 rows x 1024 u16 into units [dstu, dstu+128), 16 loads in flight.
__device__ __forceinline__ void stageH(u16* Asb, int tid, int m0,
                                       const u16* src, int dstu) {
  v4i t[16];
#pragma unroll
  for (int i = 0; i < 16; ++i) {
    int idx = tid + i * 256;
    int r = idx >> 7, ln = idx & 127;
    t[i] = cload128(src + (size_t)(m0 + r) * NU + ln * 8);
  }
  asm volatile("s_waitcnt vmcnt(0)" ::: "memory");
#pragma unroll
  for (int i = 0; i < 16; ++i) {
    int idx = tid + i * 256;
    int r = idx >> 7, ln = idx & 127;
    int u = (dstu + ln) ^ (r & 7);
    *(v4i*)(void*)(Asb + r * 2048 + u * 8) = t[i];
  }
}

// two tiles staged with ONE exposed latency: 32 loads in flight.
__device__ __forceinline__ void stageH2(u16* Asb, int tid, int m0,
                                        const u16* s0, const u16* s1) {
  v4i a[16], b[16];
#pragma unroll
  for (int i = 0; i < 16; ++i) {
    int idx = tid + i * 256;
    int r = idx >> 7, ln = idx & 127;
    a[i] = cload128(s0 + (size_t)(m0 + r) * NU + ln * 8);
  }
#pragma unroll
  for (int i = 0; i < 16; ++i) {
    int idx = tid + i * 256;
    int r = idx >> 7, ln = idx & 127;
    b[i] = cload128(s1 + (size_t)(m0 + r) * NU + ln * 8);
  }
  asm volatile("s_waitcnt vmcnt(0)" ::: "memory");
#pragma unroll
  for (int i = 0; i < 16; ++i) {
    int idx = tid + i * 256;
    int r = idx >> 7, ln = idx & 127;
    int u = ln ^ (r & 7);
    *(v4i*)(void*)(Asb + r * 2048 + u * 8) = a[i];
  }
#pragma unroll
  for (int i = 0; i < 16; ++i) {
    int idx = tid + i * 256;
    int r = idx >> 7, ln = idx & 127;
    int u = (128 + ln) ^ (r & 7);
    *(v4i*)(void*)(Asb + r * 2048 + u * 8) = b[i];
  }
}

// x(t) -> Xsb (plain loads: x is constant input)
__device__ __forceinline__ void stageX(u16* Xsb, int tid, int m0,
                                       const float* x, int t) {
#pragma unroll
  for (int i = 0; i < 4; ++i) {
    int idx = tid + i * 256;
    int ml = idx >> 5, dw = idx & 31;
    const float* sp = x + ((size_t)(m0 + ml) * NT + t) * NF + dw * 2;
    u32 v = (u32)f2bf(sp[0]) | ((u32)f2bf(sp[1]) << 16);
    *(u32*)(void*)(Xsb + ml * XS + dw * 2) = v;
  }
}

__device__ __forceinline__ v8s afragEC(const u16* Asb, const u16* Xsb,
                                       int c, int row, int quad) {
  if (c < 2)
    return *(const v8s*)(const void*)(Xsb + row * XS + c * 32 + quad * 8);
  return ldA(Asb, row, (c - 2) * 4 + quad);
}

// x-only phase (t == 0): chunks 0..1 from Xsb.
__device__ __forceinline__ void mfmaX(f32x4& acc0, f32x4& acc1, const u16* Xsb,
                                      const u16* tb, int l15, int quad, int lane) {
#pragma unroll
  for (int j = 0; j < 2; ++j) {
    v8s b  = *(const v8s*)(const void*)(tb + ((size_t)(j * 64 + lane)) * 8);
    v8s a0 = *(const v8s*)(const void*)(Xsb + l15 * XS + j * 32 + quad * 8);
    v8s a1 = *(const v8s*)(const void*)(Xsb + (16 + l15) * XS + j * 32 + quad * 8);
    acc0 = __builtin_amdgcn_mfma_f32_16x16x32_bf16(a0, b, acc0, 0, 0, 0);
    acc1 = __builtin_amdgcn_mfma_f32_16x16x32_bf16(a1, b, acc1, 0, 0, 0);
  }
}

// Encoder/cellC: 34 chunks (0..1 = x/pred from Xsb, 2..33 = h from Asb half0),
// four independent accumulator chains.
__device__ __forceinline__ void mfmaEC(f32x4& x0, f32x4& x1, f32x4& y0, f32x4& y1,
                                       const u16* Asb, const u16* Xsb, const u16* tb,
                                       int l15, int quad, int lane) {
#pragma unroll
  for (int j = 0; j < 17; ++j) {
    const int ja = j, jb = 17 + j;
    v8s ba  = *(const v8s*)(const void*)(tb + ((size_t)(ja * 64 + lane)) * 8);
    v8s aa0 = afragEC(Asb, Xsb, ja, l15, quad);
    v8s aa1 = afragEC(Asb, Xsb, ja, 16 + l15, quad);
    v8s bb  = *(const v8s*)(const void*)(tb + ((size_t)(jb * 64 + lane)) * 8);
    v8s ab0 = afragEC(Asb, Xsb, jb, l15, quad);
    v8s ab1 = afragEC(Asb, Xsb, jb, 16 + l15, quad);
    x0 = __builtin_amdgcn_mfma_f32_16x16x32_bf16(aa0, ba, x0, 0, 0, 0);
    y0 = __builtin_amdgcn_mfma_f32_16x16x32_bf16(ab0, bb, y0, 0, 0, 0);
    x1 = __builtin_amdgcn_mfma_f32_16x16x32_bf16(aa1, ba, x1, 0, 0, 0);
    y1 = __builtin_amdgcn_mfma_f32_16x16x32_bf16(ab1, bb, y1, 0, 0, 0);
  }
}

// cellR: 64 chunks, half0 = hl(s), half1 = hr(s-1) (persisted from cellC).
__device__ __forceinline__ void mfmaR(f32x4& x0, f32x4& x1, f32x4& y0, f32x4& y1,
                                      const u16* Asb, const u16* tb,
                                      int l15, int quad, int lane) {
#pragma unroll
  for (int j = 0; j < 32; ++j) {
    const int ja = j, jb = 32 + j;
    v8s ba  = *(const v8s*)(const void*)(tb + ((size_t)(ja * 64 + lane)) * 8);
    v8s aa0 = ldA(Asb, l15, ja * 4 + quad);
    v8s aa1 = ldA(Asb, 16 + l15, ja * 4 + quad);
    v8s bb  = *(const v8s*)(const void*)(tb + ((size_t)(jb * 64 + lane)) * 8);
    v8s ab0 = ldA(Asb, l15, jb * 4 + quad);
    v8s ab1 = ldA(Asb, 16 + l15, jb * 4 + quad);
    x0 = __builtin_amdgcn_mfma_f32_16x16x32_bf16(aa0, ba, x0, 0, 0, 0);
    y0 = __builtin_amdgcn_mfma_f32_16x16x32_bf16(ab0, bb, y0, 0, 0, 0);
    x1 = __builtin_amdgcn_mfma_f32_16x16x32_bf16(aa1, ba, x1, 0, 0, 0);
    y1 = __builtin_amdgcn_mfma_f32_16x16x32_bf16(ab1, bb, y1, 0, 0, 0);
  }
}

// In-block dense head from Asb half1 (hr tile): layer1 = MFMA over W1 hi+lo
// (numerically ~fp32 W1), relu via LDS; layer2 scalar fp32. Writes pred (bf16)
// to Xsb rows; leader also stores fp32 out for `step`.
__device__ __forceinline__ void dense_head(const P& p, const u16* Asb, float* d1s,
                                           u16* Xsb, int tid, int w, int lane,
                                           int quad, int l15, int m0, int step,
                                           bool wout) {
  const int rt = w >> 1, ct = w & 1;
  const int arow = rt * 16 + l15;
  const u16* wf = p.W1f;
  f32x4 acc0 = {0.f, 0.f, 0.f, 0.f}, acc1 = acc0;
#pragma unroll
  for (int k = 0; k < 16; ++k) {
    v8s b0 = *(const v8s*)(const void*)(wf + ((size_t)((2 * k) * 2 + ct) * 64 + lane) * 8);
    v8s a0 = ldA(Asb, arow, 128 + (2 * k) * 4 + quad);
    v8s b1 = *(const v8s*)(const void*)(wf + ((size_t)((2 * k + 1) * 2 + ct) * 64 + lane) * 8);
    v8s a1 = ldA(Asb, arow, 128 + (2 * k + 1) * 4 + quad);
    acc0 = __builtin_amdgcn_mfma_f32_16x16x32_bf16(a0, b0, acc0, 0, 0, 0);
    acc1 = __builtin_amdgcn_mfma_f32_16x16x32_bf16(a1, b1, acc1, 0, 0, 0);
  }
#pragma unroll
  for (int k = 0; k < 16; ++k) {  // residual (lo) part
    v8s b0 = *(const v8s*)(const void*)(wf + ((size_t)(64 + (2 * k) * 2 + ct) * 64 + lane) * 8);
    v8s a0 = ldA(Asb, arow, 128 + (2 * k) * 4 + quad);
    v8s b1 = *(const v8s*)(const void*)(wf + ((size_t)(64 + (2 * k + 1) * 2 + ct) * 64 + lane) * 8);
    v8s a1 = ldA(Asb, arow, 128 + (2 * k + 1) * 4 + quad);
    acc0 = __builtin_amdgcn_mfma_f32_16x16x32_bf16(a0, b0, acc0, 0, 0, 0);
    acc1 = __builtin_amdgcn_mfma_f32_16x16x32_bf16(a1, b1, acc1, 0, 0, 0);
  }
  acc0 += acc1;
  const int col = ct * 16 + l15;
  const float b1c = p.b1[col];
#pragma unroll
  for (int r = 0; r < 4; ++r) {
    int row = rt * 16 + quad * 4 + r;
    d1s[row * 33 + col] = fmaxf(acc0[r] + b1c, 0.f);
  }
  __syncthreads();
  const int r = tid >> 3, cb = (tid & 7) * 8;
  float s2[8];
#pragma unroll
  for (int cc = 0; cc < 8; ++cc) s2[cc] = p.b2[cb + cc];
#pragma unroll
  for (int k = 0; k < 32; ++k) {
    float dv = d1s[r * 33 + k];
    f32x4 w20 = *(const f32x4*)(const void*)(p.W2 + k * 64 + cb);
    f32x4 w21 = *(const f32x4*)(const void*)(p.W2 + k * 64 + cb + 4);
    s2[0] += dv * w20[0]; s2[1] += dv * w20[1];
    s2[2] += dv * w20[2]; s2[3] += dv * w20[3];
    s2[4] += dv * w21[0]; s2[5] += dv * w21[1];
    s2[6] += dv * w21[2]; s2[7] += dv * w21[3];
  }
#pragma unroll
  for (int cc = 0; cc < 8; ++cc) Xsb[r * XS + cb + cc] = f2bf(s2[cc]);
  if (wout) {
    float* po = p.out + ((size_t)(m0 + r) * NOUT + step) * NF + cb;
#pragma unroll
    for (int cc = 0; cc < 8; ++cc) po[cc] = s2[cc];
  }
  __syncthreads();
}

// gates tail: z -> LDS transpose (stride 18: 2-way banks = free) -> gates.
// c-state in 2 registers/thread. h packed to 8B in LDS, stored coherent.
__device__ __forceinline__ void gates_store(float* zbuf, u16* hpk,
                                            int w, int lane, int quad, int l15,
                                            int m0, int tblk,
                                            const f32x4& acc0, const f32x4& acc1,
                                            const float* bias,
                                            float cpair[2], u16* hout, bool czero) {
#pragma unroll
  for (int r = 0; r < 4; ++r) {
    zbuf[(w * 32 + quad * 4 + r) * 18 + l15]      = acc0[r];
    zbuf[(w * 32 + 16 + quad * 4 + r) * 18 + l15] = acc1[r];
  }
  __syncthreads();
#pragma unroll
  for (int rep = 0; rep < 2; ++rep) {
    int pp = lane + rep * 64;
    int ml = pp >> 2;
    int cc = pp & 3;
    int col = tblk * 4 + cc;
    int zr = (w * 32 + ml) * 18;
    float iv = zbuf[zr + 0 + cc]  + bias[col];
    float fv = zbuf[zr + 4 + cc]  + bias[1024 + col];
    float gv = zbuf[zr + 8 + cc]  + bias[2048 + col];
    float ov = zbuf[zr + 12 + cc] + bias[3072 + col];
    float cold = czero ? 0.f : cpair[rep];
    float si = 1.f / (1.f + __expf(-iv));
    float sf = 1.f / (1.f + __expf(-fv));
    float so = 1.f / (1.f + __expf(-ov));
    float e2g = __expf(2.f * gv);
    float tg  = (e2g - 1.f) / (e2g + 1.f);
    float cn  = sf * cold + si * tg;
    float e2c = __expf(2.f * cn);
    float tc  = (e2c - 1.f) / (e2c + 1.f);
    cpair[rep] = cn;
    hpk[w * 128 + ml * 4 + cc] = f2bf(so * tc);
  }
  __syncthreads();
  if (lane < 32) {
    union { u16 h4[4]; u64 q; } u;
#pragma unroll
    for (int c = 0; c < 4; ++c) u.h4[c] = hpk[w * 128 + lane * 4 + c];
    cstore64(hout + (size_t)(m0 + lane) * NU + tblk * 4, u.q);
  }
}

__global__ void __launch_bounds__(256, 1) rnn_persist(P p) {
  __shared__ __align__(16) u16 Asb[32 * 2048];  // 131,072 B
  __shared__ __align__(16) u16 Xsb[32 * XS];    //   4,608 B
  __shared__ float zbuf[128 * 18];              //   9,216 B
  __shared__ float d1s[32 * 33];                //   4,224 B
  __shared__ u16 hpack[4 * 32 * 4];             //   1,024 B

  const int tid = threadIdx.x;
  const int bid = blockIdx.x;
  const int wgn = bid & 63;
  const int mg  = bid >> 6;    // 4 independent groups of 64 blocks
  const int m0  = mg * 32;
  const int w    = tid >> 6;
  const int lane = tid & 63;
  const int quad = lane >> 4;
  const int l15  = lane & 15;
  const int tblk = wgn * 4 + w;

  const u16* tbE = p.packE + (size_t)tblk * 17408;  // [x(2 chunks); h(32 chunks)]
  const u16* tbC = p.packC + (size_t)tblk * 17408;  // [pred(2); hl(32)]
  const u16* tbR = p.packR + (size_t)tblk * 32768;  // [hl(32); hr(32)]

  float cE2[2] = {0.f, 0.f};
  u32 bno = 0;

  // ---- encoder: 256 steps ----
  stageX(Xsb, tid, m0, p.x, 0);
  for (int t = 0; t < NT; ++t) {
    const u16* hread = (t & 1) ? p.h1 : p.h0;
    u16* hwrite      = (t & 1) ? p.h0 : p.h1;
    f32x4 x0 = {0.f, 0.f, 0.f, 0.f}, x1 = x0, y0 = x0, y1 = x0;
    if (t > 0) {
      stageH(Asb, tid, m0, hread, 0);
      __syncthreads();
      mfmaEC(x0, x1, y0, y1, Asb, Xsb, tbE, l15, quad, lane);
      x0 += y0; x1 += y1;
    } else {
      __syncthreads();  // covers pre-loop stageX
      mfmaX(x0, x1, Xsb, tbE, l15, quad, lane);
    }
    gates_store(zbuf, hpack, w, lane, quad, l15, m0, tblk, x0, x1,
                p.bl, cE2, hwrite, t == 0);
    if (t + 1 < NT) stageX(Xsb, tid, m0, p.x, t + 1);  // prefetch across barrier
    ++bno; gbar(p.bar, bno, mg, wgn, tid);
  }
  // final encoder h in p.h0 (t=255 odd -> wrote p.h0)

  // ---- autoregressive: 31 steps x 2 phases (dense folded into cellC) ----
  float cL2[2] = {cE2[0], cE2[1]};
  float cR2[2] = {cE2[0], cE2[1]};
  for (int s = 1; s < NOUT; ++s) {
    const u16* hlr = (s == 1) ? p.h0 : ((s & 1) ? p.hl1 : p.hl0);  // hl(s-1)
    const u16* hrd = (s == 1) ? p.h0 : ((s & 1) ? p.hr1 : p.hr0);  // hr(s-1)
    u16* hlw = (s & 1) ? p.hl0 : p.hl1;
    u16* hrw = (s & 1) ? p.hr0 : p.hr1;

    // cellC phase: stage [hl(s-1) | hr(s-1)], dense(hr) -> pred/out, then cell.
    {
      stageH2(Asb, tid, m0, hlr, hrd);
      __syncthreads();
      dense_head(p, Asb, d1s, Xsb, tid, w, lane, quad, l15, m0, s - 1, wgn == 0);
      f32x4 x0 = {0.f, 0.f, 0.f, 0.f}, x1 = x0, y0 = x0, y1 = x0;
      mfmaEC(x0, x1, y0, y1, Asb, Xsb, tbC, l15, quad, lane);
      x0 += y0; x1 += y1;
      gates_store(zbuf, hpack, w, lane, quad, l15, m0, tblk, x0, x1,
                  p.bc, cL2, hlw, false);
    }
    ++bno; gbar(p.bar, bno, mg, wgn, tid);

    // cellR phase: stage only hl(s) into half0 (half1 still holds hr(s-1)).
    {
      stageH(Asb, tid, m0, hlw, 0);
      __syncthreads();
      f32x4 x0 = {0.f, 0.f, 0.f, 0.f}, x1 = x0, y0 = x0, y1 = x0;
      mfmaR(x0, x1, y0, y1, Asb, tbR, l15, quad, lane);
      x0 += y0; x1 += y1;
      gates_store(zbuf, hpack, w, lane, quad, l15, m0, tblk, x0, x1,
                  p.br, cR2, hrw, false);
    }
    ++bno; gbar(p.bar, bno, mg, wgn, tid);
  }

  // epilogue: out[:,31,:] = dense(hr(31)); leaders only (no barrier needed).
  if (wgn == 0) {
    stageH(Asb, tid, m0, p.hr0, 128);  // hr(31): s=31 odd -> p.hr0
    __syncthreads();
    dense_head(p, Asb, d1s, Xsb, tid, w, lane, quad, l15, m0, NOUT - 1, true);
  }
}

extern "C" void kernel_launch(void* const* d_in, const int* in_sizes, int n_in,
                              void* d_out, int out_size, void* d_ws, size_t ws_size,
                              hipStream_t stream) {
  const float* x  = (const float*)d_in[0];
  const float* Wl = (const float*)d_in[1];
  const float* Rl = (const float*)d_in[2];
  const float* bl = (const float*)d_in[3];
  const float* Wc = (const float*)d_in[4];
  const float* Rc = (const float*)d_in[5];
  const float* bc = (const float*)d_in[6];
  const float* Wr = (const float*)d_in[7];
  const float* Rr = (const float*)d_in[8];
  const float* br = (const float*)d_in[9];
  const float* W1 = (const float*)d_in[10];
  const float* b1 = (const float*)d_in[11];
  const float* W2 = (const float*)d_in[12];
  const float* b2 = (const float*)d_in[13];

  char* ws = (char*)d_ws;
  size_t off = 0;
  auto alloc = [&](size_t bytes) -> void* {
    void* r = ws + off;
    off += (bytes + 255) & ~(size_t)255;
    return r;
  };
  const size_t szPackE = (size_t)256 * 17408 * 2;  // 8,912,896
  const size_t szPackR = (size_t)256 * 32768 * 2;  // 16,777,216
  u16* packE = (u16*)alloc(szPackE);
  u16* packC = (u16*)alloc(szPackE);
  u16* packR = (u16*)alloc(szPackR);
  u16* W1f   = (u16*)alloc((size_t)128 * 64 * 8 * 2);  // 131,072
  u16* h0  = (u16*)alloc(NB * NU * 2);
  u16* h1  = (u16*)alloc(NB * NU * 2);
  u16* hl0 = (u16*)alloc(NB * NU * 2);
  u16* hl1 = (u16*)alloc(NB * NU * 2);
  u16* hr0 = (u16*)alloc(NB * NU * 2);
  u16* hr1 = (u16*)alloc(NB * NU * 2);
  u32* bar = (u32*)alloc(2 * NBLK * FPAD * 4);

  init_bar<<<dim3(64), dim3(256), 0, stream>>>(bar);
  pack_weights<<<dim3(128 * 17), dim3(256), 0, stream>>>(Wl, Rl, 64, 17, packE);
  pack_weights<<<dim3(128 * 17), dim3(256), 0, stream>>>(Wc, Rc, 64, 17, packC);
  pack_weights<<<dim3(128 * 32), dim3(256), 0, stream>>>(Wr, Rr, 1024, 32, packR);
  pack_w1<<<dim3(32), dim3(256), 0, stream>>>(W1, W1f);

  static P p;
  p.x = x;
  p.packE = packE; p.packC = packC; p.packR = packR; p.W1f = W1f;
  p.bl = bl; p.bc = bc; p.br = br;
  p.b1 = b1; p.W2 = W2; p.b2 = b2;
  p.h0 = h0; p.h1 = h1; p.hl0 = hl0; p.hl1 = hl1; p.hr0 = hr0; p.hr1 = hr1;
  p.out = (float*)d_out;
  p.bar = bar;

  rnn_persist<<<dim3(NBLK), dim3(256), 0, stream>>>(p);
}

// Round 6
// 3264.112 us; speedup vs baseline: 1.5624x; 1.3094x over previous
//
#include <hip/hip_runtime.h>

typedef unsigned short u16;
typedef unsigned int u32;
typedef unsigned long long u64;
typedef short v8s __attribute__((ext_vector_type(8)));
typedef int v4i __attribute__((ext_vector_type(4)));
typedef float f32x4 __attribute__((ext_vector_type(4)));

#define NB 128
#define NU 1024
#define NF 64
#define NT 256
#define NOUT 32
#define NBLK 256
#define XS 72       // LDS X row stride in u16: 64 + 8 pad
#define FPAD 32     // u32 per barrier flag line (128 B) -> private MALL line
#define GO_OFF (NBLK * FPAD)
#define ZBS 66      // zb row stride (f32): 64 + 2 -> 2-way banks on write & read

__device__ __forceinline__ u16 f2bf(float f) {
  union { float f; u32 u; } v; v.f = f;
  u32 x = v.u;
  return (u16)((x + 0x7fffu + ((x >> 16) & 1u)) >> 16);
}
__device__ __forceinline__ float bf2f(u16 u) {
  union { u32 u; float f; } v; v.u = ((u32)u) << 16;
  return v.f;
}

// --- coherent (agent-scope, fence-free) access helpers ---
__device__ __forceinline__ void cstore32(u32* p, u32 v) {
  __hip_atomic_store(p, v, __ATOMIC_RELAXED, __HIP_MEMORY_SCOPE_AGENT);
}
// 16B coherent load: sc0 sc1 reads at the coherence point.
// Result valid only after an explicit s_waitcnt vmcnt(0).
__device__ __forceinline__ v4i cload128(const void* p) {
  v4i r;
  asm volatile("global_load_dwordx4 %0, %1, off sc0 sc1" : "=v"(r) : "v"(p) : "memory");
  return r;
}

// Hierarchical per-group barrier (r4-proven): arrival on private 128B lines;
// leader block's wave0 polls 64 lines (cached-once, s_sleep-throttled), then
// releases per-block go-lines; non-leaders poll their own go line.
__device__ __forceinline__ void gbar(u32* bar, u32 gen, int grp, int wgn, int tid) {
  asm volatile("s_waitcnt vmcnt(0)" ::: "memory");
  __syncthreads();
  const int bid = grp * 64 + wgn;
  if (tid == 0)
    __hip_atomic_store(&bar[bid * FPAD], gen, __ATOMIC_RELAXED, __HIP_MEMORY_SCOPE_AGENT);
  u32* go = bar + GO_OFF;
  if (wgn == 0) {
    if (tid < 64) {
      const u32* fl = bar + (size_t)(grp * 64 + tid) * FPAD;
      bool ok = false;
      u32 spin = 0;
      for (;;) {
        if (!ok)
          ok = __hip_atomic_load(fl, __ATOMIC_RELAXED, __HIP_MEMORY_SCOPE_AGENT) >= gen;
        if (__all(ok)) break;
        __builtin_amdgcn_s_sleep(2);
        if (++spin > 2000000u) break;  // escape hatch
      }
      __hip_atomic_store(&go[(grp * 64 + tid) * FPAD], gen, __ATOMIC_RELAXED,
                         __HIP_MEMORY_SCOPE_AGENT);
    }
  } else if (tid == 0) {
    const u32* fl = go + (size_t)bid * FPAD;
    u32 spin = 0;
    while (__hip_atomic_load(fl, __ATOMIC_RELAXED, __HIP_MEMORY_SCOPE_AGENT) < gen) {
      __builtin_amdgcn_s_sleep(2);
      if (++spin > 2000000u) break;  // escape hatch
    }
  }
  __syncthreads();
  asm volatile("" ::: "memory");
}

__global__ void init_bar(u32* bar) {
  int i = blockIdx.x * 256 + threadIdx.x;
  if (i < 2 * NBLK * FPAD) bar[i] = 0;
}

// Pack [top(ktop x 4096); R(1024 x 4096)] into MFMA-B-fragment-major bf16 with
// gate-permuted columns: z' col (t*16 + q*4 + c) <- orig col (q*1024 + t*4 + c).
__global__ void pack_weights(const float* __restrict__ top, const float* __restrict__ R,
                             int ktop, int nchunk, u16* __restrict__ dst) {
  int line = blockIdx.x * 256 + threadIdx.x;
  int l = line & 63;
  int rest = line >> 6;
  int s = rest & 1; rest >>= 1;
  int kk = rest % nchunk;
  int t  = rest / nchunk;
  if (t >= 256) return;
  int kbase = kk * 64 + s * 32 + (l >> 4) * 8;
  int col = ((l >> 2) & 3) * 1024 + t * 4 + (l & 3);
  v8s o;
#pragma unroll
  for (int j = 0; j < 8; ++j) {
    int k = kbase + j;
    float v = (k < ktop) ? top[(size_t)k * 4096 + col]
                         : R[(size_t)(k - ktop) * 4096 + col];
    o[j] = (short)f2bf(v);
  }
  *(v8s*)(void*)(dst + (size_t)line * 8) = o;
}

// Pack W1 (1024 x 32 fp32) as bf16 hi (lines 0..63) + bf16 residual lo
// (lines 64..127), fragment-major.
__global__ void pack_w1(const float* __restrict__ W1, u16* __restrict__ dst) {
  int id = blockIdx.x * 256 + threadIdx.x;  // 8192 work items
  int lane = id & 63;
  int line = id >> 6;      // 0..127
  int res = line >> 6;     // 0=hi, 1=lo
  int cl = line & 63;
  int c = cl >> 1, nt = cl & 1;
  int krow = c * 32 + ((lane >> 4) * 8);
  int col = nt * 16 + (lane & 15);
  v8s o;
#pragma unroll
  for (int j = 0; j < 8; ++j) {
    float v = W1[(size_t)(krow + j) * 32 + col];
    u16 hi = f2bf(v);
    o[j] = (short)(res ? f2bf(v - bf2f(hi)) : hi);
  }
  *(v8s*)(void*)(dst + (size_t)id * 8) = o;
}

struct P {
  const float* x;
  const u16 *packE, *packC, *packR, *W1f;
  const float *bl, *bc, *br, *b1, *W2, *b2;
  u16 *hxE0, *hxE1, *hxL0, *hxL1, *hxR0, *hxR1;  // packed h-exchange buffers
  float* out;
  u32* bar;
};

// ---- Asb: [32 rows][2048 u16], row stride 4096 B. XOR swizzle on 16B units:
// phys_unit = unit ^ (row & 7). Unit u of row r holds k-range [u*8, u*8+8).
__device__ __forceinline__ v8s ldA(const u16* Asb, int row, int unit) {
  return *(const v8s*)(const void*)(Asb + row * 2048 + ((unit ^ (row & 7)) * 8));
}

// ---- h-exchange: block b's tile packed at hx + b*512 u16 as [32 rows][16 cols]
// (h-cols [16b_local, 16b_local+16)). Producer stores 256 coalesced u32;
// consumer loads are LINEAR: 16B-unit q -> u16 offset q*8.
__device__ __forceinline__ void stageHX(u16* Asb, int tid, const u16* hx, int dstu) {
  v4i t[16];
#pragma unroll
  for (int i = 0; i < 16; ++i) {
    int q = tid + i * 256;
    t[i] = cload128(hx + (size_t)q * 8);
  }
  asm volatile("s_waitcnt vmcnt(0)" ::: "memory");
#pragma unroll
  for (int i = 0; i < 16; ++i) {
    int q = tid + i * 256;
    int sb = q >> 6, rem = q & 63;
    int r = rem >> 1, c8 = rem & 1;
    int u = (dstu + sb * 2 + c8) ^ (r & 7);
    *(v4i*)(void*)(Asb + r * 2048 + u * 8) = t[i];
  }
}

// two exchange tiles staged with ONE exposed latency: 32 loads in flight.
__device__ __forceinline__ void stageH2X(u16* Asb, int tid,
                                         const u16* hxa, const u16* hxb) {
  v4i a[16], b[16];
#pragma unroll
  for (int i = 0; i < 16; ++i) {
    int q = tid + i * 256;
    a[i] = cload128(hxa + (size_t)q * 8);
  }
#pragma unroll
  for (int i = 0; i < 16; ++i) {
    int q = tid + i * 256;
    b[i] = cload128(hxb + (size_t)q * 8);
  }
  asm volatile("s_waitcnt vmcnt(0)" ::: "memory");
#pragma unroll
  for (int i = 0; i < 16; ++i) {
    int q = tid + i * 256;
    int sb = q >> 6, rem = q & 63;
    int r = rem >> 1, c8 = rem & 1;
    int u = (sb * 2 + c8) ^ (r & 7);
    *(v4i*)(void*)(Asb + r * 2048 + u * 8) = a[i];
  }
#pragma unroll
  for (int i = 0; i < 16; ++i) {
    int q = tid + i * 256;
    int sb = q >> 6, rem = q & 63;
    int r = rem >> 1, c8 = rem & 1;
    int u = (128 + sb * 2 + c8) ^ (r & 7);
    *(v4i*)(void*)(Asb + r * 2048 + u * 8) = b[i];
  }
}

// x(t) -> Xsb (plain loads: x is constant input)
__device__ __forceinline__ void stageX(u16* Xsb, int tid, int m0,
                                       const float* x, int t) {
#pragma unroll
  for (int i = 0; i < 4; ++i) {
    int idx = tid + i * 256;
    int ml = idx >> 5, dw = idx & 31;
    const float* sp = x + ((size_t)(m0 + ml) * NT + t) * NF + dw * 2;
    u32 v = (u32)f2bf(sp[0]) | ((u32)f2bf(sp[1]) << 16);
    *(u32*)(void*)(Xsb + ml * XS + dw * 2) = v;
  }
}

// ---- split-K MFMA: warp w handles chunks j == w (mod 4) for ALL FOUR of the
// block's col-tiles. 8 independent accumulator chains; LDS A-reads /4 vs
// per-warp-tile decomposition. XCH = leading chunks served from Xsb.
template <int NCH, int XCH>
__device__ __forceinline__ void mfmaSK(f32x4 (&acc)[4][2], const u16* Asb,
                                       const u16* Xsb, const u16* pack,
                                       int linesz, int tile0,
                                       int w, int lane, int quad, int l15) {
  const u16* tb0 = pack + (size_t)(tile0 + 0) * linesz;
  const u16* tb1 = pack + (size_t)(tile0 + 1) * linesz;
  const u16* tb2 = pack + (size_t)(tile0 + 2) * linesz;
  const u16* tb3 = pack + (size_t)(tile0 + 3) * linesz;
  for (int j = w; j < NCH; j += 4) {
    v8s a0, a1;
    if (XCH > 0 && j < XCH) {
      a0 = *(const v8s*)(const void*)(Xsb + l15 * XS + j * 32 + quad * 8);
      a1 = *(const v8s*)(const void*)(Xsb + (16 + l15) * XS + j * 32 + quad * 8);
    } else {
      int u = (j - XCH) * 4 + quad;
      a0 = ldA(Asb, l15, u);
      a1 = ldA(Asb, 16 + l15, u);
    }
    size_t bo = (size_t)(j * 64 + lane) * 8;
    v8s b0 = *(const v8s*)(const void*)(tb0 + bo);
    v8s b1 = *(const v8s*)(const void*)(tb1 + bo);
    v8s b2 = *(const v8s*)(const void*)(tb2 + bo);
    v8s b3 = *(const v8s*)(const void*)(tb3 + bo);
    acc[0][0] = __builtin_amdgcn_mfma_f32_16x16x32_bf16(a0, b0, acc[0][0], 0, 0, 0);
    acc[1][0] = __builtin_amdgcn_mfma_f32_16x16x32_bf16(a0, b1, acc[1][0], 0, 0, 0);
    acc[2][0] = __builtin_amdgcn_mfma_f32_16x16x32_bf16(a0, b2, acc[2][0], 0, 0, 0);
    acc[3][0] = __builtin_amdgcn_mfma_f32_16x16x32_bf16(a0, b3, acc[3][0], 0, 0, 0);
    acc[0][1] = __builtin_amdgcn_mfma_f32_16x16x32_bf16(a1, b0, acc[0][1], 0, 0, 0);
    acc[1][1] = __builtin_amdgcn_mfma_f32_16x16x32_bf16(a1, b1, acc[1][1], 0, 0, 0);
    acc[2][1] = __builtin_amdgcn_mfma_f32_16x16x32_bf16(a1, b2, acc[2][1], 0, 0, 0);
    acc[3][1] = __builtin_amdgcn_mfma_f32_16x16x32_bf16(a1, b3, acc[3][1], 0, 0, 0);
  }
}

// gates tail with split-K reduce. Partial-z layout (CORRECTED r5->r6):
//   MFMA C/D: batch row = quad*4+r (+16 for the a1 half), weight col = l15.
//   zb[(wsrc*32 + batch_row) * ZBS + tile*16 + wcol]   (overlaid on Asb; all
//   Asb contents dead post-MFMA). Write banks: (8*quad + l15) mod 32 = 2-way;
//   read banks: (2*ml + cc) mod 32 = 2-way -> both free.
__device__ __forceinline__ void gates_store(float* zb, u16* hpk,
                                            int w, int lane, int quad, int l15,
                                            int wgn, int bid,
                                            const f32x4 (&acc)[4][2],
                                            const float* bias,
                                            float cpair[2], u16* hxout, bool czero) {
  __syncthreads();  // all warps done reading Asb/Xsb before overlay write
#pragma unroll
  for (int tt = 0; tt < 4; ++tt)
#pragma unroll
    for (int rt = 0; rt < 2; ++rt)
#pragma unroll
      for (int r = 0; r < 4; ++r)
        zb[(size_t)(w * 32 + rt * 16 + quad * 4 + r) * ZBS + tt * 16 + l15] =
            acc[tt][rt][r];
  __syncthreads();
  const int tblk = wgn * 4 + w;
#pragma unroll
  for (int rep = 0; rep < 2; ++rep) {
    int pp = lane + rep * 64;
    int ml = pp >> 2;
    int cc = pp & 3;
    int col = tblk * 4 + cc;
    float zg[4];
#pragma unroll
    for (int g = 0; g < 4; ++g) {
      int zc = w * 16 + g * 4 + cc;  // this warp reduces its own tile's cols
      float s = zb[(size_t)(0 * 32 + ml) * ZBS + zc] +
                zb[(size_t)(1 * 32 + ml) * ZBS + zc] +
                zb[(size_t)(2 * 32 + ml) * ZBS + zc] +
                zb[(size_t)(3 * 32 + ml) * ZBS + zc];
      zg[g] = s + bias[g * 1024 + col];
    }
    float cold = czero ? 0.f : cpair[rep];
    float si = 1.f / (1.f + __expf(-zg[0]));
    float sf = 1.f / (1.f + __expf(-zg[1]));
    float so = 1.f / (1.f + __expf(-zg[3]));
    float e2g = __expf(2.f * zg[2]);
    float tg  = (e2g - 1.f) / (e2g + 1.f);
    float cn  = sf * cold + si * tg;
    float e2c = __expf(2.f * cn);
    float tc  = (e2c - 1.f) / (e2c + 1.f);
    cpair[rep] = cn;
    hpk[w * 128 + ml * 4 + cc] = f2bf(so * tc);
  }
  __syncthreads();
  {
    int tid = w * 64 + lane;
    int r = tid >> 3, c2 = tid & 7;
    int wsrc = c2 >> 1;
    u32 v = *(const u32*)(const void*)(hpk + wsrc * 128 + r * 4 + (c2 & 1) * 2);
    cstore32((u32*)(void*)(hxout + (size_t)bid * 512) + r * 8 + c2, v);
  }
}

// In-block dense head from Asb half1 (hr tile): layer1 = MFMA over W1 hi+lo,
// relu via LDS; layer2 scalar fp32. Writes pred (bf16) to Xsb; leader also
// stores fp32 out for `step`.
__device__ __forceinline__ void dense_head(const P& p, const u16* Asb, float* d1s,
                                           u16* Xsb, int tid, int w, int lane,
                                           int quad, int l15, int m0, int step,
                                           bool wout) {
  const int rt = w >> 1, ct = w & 1;
  const int arow = rt * 16 + l15;
  const u16* wf = p.W1f;
  f32x4 acc0 = {0.f, 0.f, 0.f, 0.f}, acc1 = acc0;
#pragma unroll
  for (int k = 0; k < 16; ++k) {
    v8s b0 = *(const v8s*)(const void*)(wf + ((size_t)((2 * k) * 2 + ct) * 64 + lane) * 8);
    v8s a0 = ldA(Asb, arow, 128 + (2 * k) * 4 + quad);
    v8s b1 = *(const v8s*)(const void*)(wf + ((size_t)((2 * k + 1) * 2 + ct) * 64 + lane) * 8);
    v8s a1 = ldA(Asb, arow, 128 + (2 * k + 1) * 4 + quad);
    acc0 = __builtin_amdgcn_mfma_f32_16x16x32_bf16(a0, b0, acc0, 0, 0, 0);
    acc1 = __builtin_amdgcn_mfma_f32_16x16x32_bf16(a1, b1, acc1, 0, 0, 0);
  }
#pragma unroll
  for (int k = 0; k < 16; ++k) {  // residual (lo) part
    v8s b0 = *(const v8s*)(const void*)(wf + ((size_t)(64 + (2 * k) * 2 + ct) * 64 + lane) * 8);
    v8s a0 = ldA(Asb, arow, 128 + (2 * k) * 4 + quad);
    v8s b1 = *(const v8s*)(const void*)(wf + ((size_t)(64 + (2 * k + 1) * 2 + ct) * 64 + lane) * 8);
    v8s a1 = ldA(Asb, arow, 128 + (2 * k + 1) * 4 + quad);
    acc0 = __builtin_amdgcn_mfma_f32_16x16x32_bf16(a0, b0, acc0, 0, 0, 0);
    acc1 = __builtin_amdgcn_mfma_f32_16x16x32_bf16(a1, b1, acc1, 0, 0, 0);
  }
  acc0 += acc1;
  const int col = ct * 16 + l15;
  const float b1c = p.b1[col];
#pragma unroll
  for (int r = 0; r < 4; ++r) {
    int row = rt * 16 + quad * 4 + r;
    d1s[row * 33 + col] = fmaxf(acc0[r] + b1c, 0.f);
  }
  __syncthreads();
  const int r = tid >> 3, cb = (tid & 7) * 8;
  float s2[8];
#pragma unroll
  for (int cc = 0; cc < 8; ++cc) s2[cc] = p.b2[cb + cc];
#pragma unroll
  for (int k = 0; k < 32; ++k) {
    float dv = d1s[r * 33 + k];
    f32x4 w20 = *(const f32x4*)(const void*)(p.W2 + k * 64 + cb);
    f32x4 w21 = *(const f32x4*)(const void*)(p.W2 + k * 64 + cb + 4);
    s2[0] += dv * w20[0]; s2[1] += dv * w20[1];
    s2[2] += dv * w20[2]; s2[3] += dv * w20[3];
    s2[4] += dv * w21[0]; s2[5] += dv * w21[1];
    s2[6] += dv * w21[2]; s2[7] += dv * w21[3];
  }
#pragma unroll
  for (int cc = 0; cc < 8; ++cc) Xsb[r * XS + cb + cc] = f2bf(s2[cc]);
  if (wout) {
    float* po = p.out + ((size_t)(m0 + r) * NOUT + step) * NF + cb;
#pragma unroll
    for (int cc = 0; cc < 8; ++cc) po[cc] = s2[cc];
  }
  __syncthreads();
}

__global__ void __launch_bounds__(256, 1) rnn_persist(P p) {
  __shared__ __align__(16) u16 Asb[32 * 2048];  // 131,072 B (zb overlays start)
  __shared__ __align__(16) u16 Xsb[32 * XS];    //   4,608 B
  __shared__ float d1s[32 * 33];                //   4,224 B
  __shared__ u16 hpack[512];                    //   1,024 B
  float* zb = (float*)(void*)Asb;               // 128*ZBS f32 = 33,792 B

  const int tid = threadIdx.x;
  const int bid = blockIdx.x;
  const int wgn = bid & 63;
  const int mg  = bid >> 6;    // 4 independent groups of 64 blocks
  const int m0  = mg * 32;
  const int w    = tid >> 6;
  const int lane = tid & 63;
  const int quad = lane >> 4;
  const int l15  = lane & 15;
  const int tile0 = wgn * 4;
  const size_t gsl = (size_t)mg * 64 * 512;  // group slice offset in hx (u16)

  float cE2[2] = {0.f, 0.f};
  u32 bno = 0;

  // ---- encoder: 256 steps ----
  stageX(Xsb, tid, m0, p.x, 0);
  for (int t = 0; t < NT; ++t) {
    const u16* hread = ((t & 1) ? p.hxE1 : p.hxE0) + gsl;
    u16* hwrite      = (t & 1) ? p.hxE0 : p.hxE1;
    f32x4 acc[4][2];
#pragma unroll
    for (int a = 0; a < 4; ++a)
#pragma unroll
      for (int b = 0; b < 2; ++b) acc[a][b] = (f32x4){0.f, 0.f, 0.f, 0.f};
    if (t > 0) {
      stageHX(Asb, tid, hread, 0);
      __syncthreads();
      mfmaSK<34, 2>(acc, Asb, Xsb, p.packE, 17408, tile0, w, lane, quad, l15);
    } else {
      __syncthreads();  // covers pre-loop stageX
      mfmaSK<2, 2>(acc, Asb, Xsb, p.packE, 17408, tile0, w, lane, quad, l15);
    }
    gates_store(zb, hpack, w, lane, quad, l15, wgn, bid, acc,
                p.bl, cE2, hwrite, t == 0);
    if (t + 1 < NT) stageX(Xsb, tid, m0, p.x, t + 1);  // prefetch across barrier
    ++bno; gbar(p.bar, bno, mg, wgn, tid);
  }
  // final encoder h in hxE0 (t=255 odd -> wrote hxE0)

  // ---- autoregressive: 31 steps x 2 phases (dense folded into cellC) ----
  float cL2[2] = {cE2[0], cE2[1]};
  float cR2[2] = {cE2[0], cE2[1]};
  for (int s = 1; s < NOUT; ++s) {
    const u16* hlr = ((s == 1) ? p.hxE0 : ((s & 1) ? p.hxL1 : p.hxL0)) + gsl;
    const u16* hrd = ((s == 1) ? p.hxE0 : ((s & 1) ? p.hxR1 : p.hxR0)) + gsl;
    u16* hlw = (s & 1) ? p.hxL0 : p.hxL1;
    u16* hrw = (s & 1) ? p.hxR0 : p.hxR1;

    // cellC phase: stage [hl(s-1) | hr(s-1)], dense(hr) -> pred/out, cell.
    {
      stageH2X(Asb, tid, hlr, hrd);
      __syncthreads();
      dense_head(p, Asb, d1s, Xsb, tid, w, lane, quad, l15, m0, s - 1, wgn == 0);
      f32x4 acc[4][2];
#pragma unroll
      for (int a = 0; a < 4; ++a)
#pragma unroll
        for (int b = 0; b < 2; ++b) acc[a][b] = (f32x4){0.f, 0.f, 0.f, 0.f};
      mfmaSK<34, 2>(acc, Asb, Xsb, p.packC, 17408, tile0, w, lane, quad, l15);
      gates_store(zb, hpack, w, lane, quad, l15, wgn, bid, acc,
                  p.bc, cL2, hlw, false);
    }
    ++bno; gbar(p.bar, bno, mg, wgn, tid);

    // cellR phase: stage [hl(s) | hr(s-1)] (re-staged: zb overlay dirtied Asb).
    {
      stageH2X(Asb, tid, hlw + gsl, hrd);
      __syncthreads();
      f32x4 acc[4][2];
#pragma unroll
      for (int a = 0; a < 4; ++a)
#pragma unroll
        for (int b = 0; b < 2; ++b) acc[a][b] = (f32x4){0.f, 0.f, 0.f, 0.f};
      mfmaSK<64, 0>(acc, Asb, Xsb, p.packR, 32768, tile0, w, lane, quad, l15);
      gates_store(zb, hpack, w, lane, quad, l15, wgn, bid, acc,
                  p.br, cR2, hrw, false);
    }
    ++bno; gbar(p.bar, bno, mg, wgn, tid);
  }

  // epilogue: out[:,31,:] = dense(hr(31)); leaders only.
  if (wgn == 0) {
    stageHX(Asb, tid, p.hxR0 + gsl, 128);  // hr(31): s=31 odd -> hxR0
    __syncthreads();
    dense_head(p, Asb, d1s, Xsb, tid, w, lane, quad, l15, m0, NOUT - 1, true);
  }
}

extern "C" void kernel_launch(void* const* d_in, const int* in_sizes, int n_in,
                              void* d_out, int out_size, void* d_ws, size_t ws_size,
                              hipStream_t stream) {
  const float* x  = (const float*)d_in[0];
  const float* Wl = (const float*)d_in[1];
  const float* Rl = (const float*)d_in[2];
  const float* bl = (const float*)d_in[3];
  const float* Wc = (const float*)d_in[4];
  const float* Rc = (const float*)d_in[5];
  const float* bc = (const float*)d_in[6];
  const float* Wr = (const float*)d_in[7];
  const float* Rr = (const float*)d_in[8];
  const float* br = (const float*)d_in[9];
  const float* W1 = (const float*)d_in[10];
  const float* b1 = (const float*)d_in[11];
  const float* W2 = (const float*)d_in[12];
  const float* b2 = (const float*)d_in[13];

  char* ws = (char*)d_ws;
  size_t off = 0;
  auto alloc = [&](size_t bytes) -> void* {
    void* r = ws + off;
    off += (bytes + 255) & ~(size_t)255;
    return r;
  };
  const size_t szPackE = (size_t)256 * 17408 * 2;  // 8,912,896
  const size_t szPackR = (size_t)256 * 32768 * 2;  // 16,777,216
  const size_t szHx    = (size_t)NBLK * 512 * 2;   // 262,144
  u16* packE = (u16*)alloc(szPackE);
  u16* packC = (u16*)alloc(szPackE);
  u16* packR = (u16*)alloc(szPackR);
  u16* W1f   = (u16*)alloc((size_t)128 * 64 * 8 * 2);  // 131,072
  u16* hxE0 = (u16*)alloc(szHx);
  u16* hxE1 = (u16*)alloc(szHx);
  u16* hxL0 = (u16*)alloc(szHx);
  u16* hxL1 = (u16*)alloc(szHx);
  u16* hxR0 = (u16*)alloc(szHx);
  u16* hxR1 = (u16*)alloc(szHx);
  u32* bar = (u32*)alloc(2 * NBLK * FPAD * 4);

  init_bar<<<dim3(64), dim3(256), 0, stream>>>(bar);
  pack_weights<<<dim3(128 * 17), dim3(256), 0, stream>>>(Wl, Rl, 64, 17, packE);
  pack_weights<<<dim3(128 * 17), dim3(256), 0, stream>>>(Wc, Rc, 64, 17, packC);
  pack_weights<<<dim3(128 * 32), dim3(256), 0, stream>>>(Wr, Rr, 1024, 32, packR);
  pack_w1<<<dim3(32), dim3(256), 0, stream>>>(W1, W1f);

  static P p;
  p.x = x;
  p.packE = packE; p.packC = packC; p.packR = packR; p.W1f = W1f;
  p.bl = bl; p.bc = bc; p.br = br;
  p.b1 = b1; p.W2 = W2; p.b2 = b2;
  p.hxE0 = hxE0; p.hxE1 = hxE1;
  p.hxL0 = hxL0; p.hxL1 = hxL1;
  p.hxR0 = hxR0; p.hxR1 = hxR1;
  p.out = (float*)d_out;
  p.bar = bar;

  rnn_persist<<<dim3(NBLK), dim3(256), 0, stream>>>(p);
}

// Round 7
// 3013.797 us; speedup vs baseline: 1.6922x; 1.0831x over previous
//
#include <hip/hip_runtime.h>

typedef unsigned short u16;
typedef unsigned int u32;
typedef unsigned long long u64;
typedef short v8s __attribute__((ext_vector_type(8)));
typedef int v4i __attribute__((ext_vector_type(4)));
typedef float f32x4 __attribute__((ext_vector_type(4)));

#define NB 128
#define NU 1024
#define NF 64
#define NT 256
#define NOUT 32
#define NBLK 256
#define XS 72       // LDS X row stride in u16: 64 + 8 pad
#define FPAD 32     // u32 per barrier flag line (128 B) -> private MALL line
#define ZBS 66      // zb row stride (f32): 64 + 2 -> 2-way banks on write & read

__device__ __forceinline__ u16 f2bf(float f) {
  union { float f; u32 u; } v; v.f = f;
  u32 x = v.u;
  return (u16)((x + 0x7fffu + ((x >> 16) & 1u)) >> 16);
}
__device__ __forceinline__ float bf2f(u16 u) {
  union { u32 u; float f; } v; v.u = ((u32)u) << 16;
  return v.f;
}

// --- coherent (agent-scope, fence-free) access helpers ---
__device__ __forceinline__ void cstore32(u32* p, u32 v) {
  __hip_atomic_store(p, v, __ATOMIC_RELAXED, __HIP_MEMORY_SCOPE_AGENT);
}
// 16B coherent load: sc0 sc1 reads at the coherence point.
// Result valid only after an explicit s_waitcnt vmcnt(0).
__device__ __forceinline__ v4i cload128(const void* p) {
  v4i r;
  asm volatile("global_load_dwordx4 %0, %1, off sc0 sc1" : "=v"(r) : "v"(p) : "memory");
  return r;
}

// ---- fused stage-barrier protocol (r7) ----
// End of every phase: publish() = drain + block sync + store own flag (=gen).
// Start of a staged phase: each wave polls ITS 16 producers' flags (lanes 0..15,
// load-once cached, s_sleep-throttled), then immediately loads those producers'
// tiles. No leader, no go-phase: 2 serialized MALL hops total, and arrival
// detection overlaps load issue per slice. Block-level skew stays <= 1 phase
// (stage completes only after all 4 slices = all 64 flags seen), so
// double-buffered exchange remains race-free.
__device__ __forceinline__ void publish(u32* bar, u32 gen, int bid, int tid) {
  asm volatile("s_waitcnt vmcnt(0)" ::: "memory");
  __syncthreads();
  if (tid == 0)
    __hip_atomic_store(&bar[bid * FPAD], gen, __ATOMIC_RELAXED, __HIP_MEMORY_SCOPE_AGENT);
}

__device__ __forceinline__ void pollslice(const u32* bar, u32 gen, int grp,
                                          int w, int lane) {
  const u32* fl = bar + (size_t)(grp * 64 + w * 16 + (lane & 15)) * FPAD;
  bool ok = (lane >= 16);
  u32 spin = 0;
  for (;;) {
    if (!ok)
      ok = __hip_atomic_load(fl, __ATOMIC_RELAXED, __HIP_MEMORY_SCOPE_AGENT) >= gen;
    if (__all(ok)) break;
    __builtin_amdgcn_s_sleep(1);
    if (++spin > 4000000u) break;  // escape hatch
  }
}

__global__ void init_bar(u32* bar) {
  int i = blockIdx.x * 256 + threadIdx.x;
  if (i < 2 * NBLK * FPAD) bar[i] = 0;
}

// Pack [top(ktop x 4096); R(1024 x 4096)] into MFMA-B-fragment-major bf16 with
// gate-permuted columns: z' col (t*16 + q*4 + c) <- orig col (q*1024 + t*4 + c).
__global__ void pack_weights(const float* __restrict__ top, const float* __restrict__ R,
                             int ktop, int nchunk, u16* __restrict__ dst) {
  int line = blockIdx.x * 256 + threadIdx.x;
  int l = line & 63;
  int rest = line >> 6;
  int s = rest & 1; rest >>= 1;
  int kk = rest % nchunk;
  int t  = rest / nchunk;
  if (t >= 256) return;
  int kbase = kk * 64 + s * 32 + (l >> 4) * 8;
  int col = ((l >> 2) & 3) * 1024 + t * 4 + (l & 3);
  v8s o;
#pragma unroll
  for (int j = 0; j < 8; ++j) {
    int k = kbase + j;
    float v = (k < ktop) ? top[(size_t)k * 4096 + col]
                         : R[(size_t)(k - ktop) * 4096 + col];
    o[j] = (short)f2bf(v);
  }
  *(v8s*)(void*)(dst + (size_t)line * 8) = o;
}

// Pack W1 (1024 x 32 fp32) as bf16 hi (lines 0..63) + bf16 residual lo
// (lines 64..127), fragment-major.
__global__ void pack_w1(const float* __restrict__ W1, u16* __restrict__ dst) {
  int id = blockIdx.x * 256 + threadIdx.x;  // 8192 work items
  int lane = id & 63;
  int line = id >> 6;      // 0..127
  int res = line >> 6;     // 0=hi, 1=lo
  int cl = line & 63;
  int c = cl >> 1, nt = cl & 1;
  int krow = c * 32 + ((lane >> 4) * 8);
  int col = nt * 16 + (lane & 15);
  v8s o;
#pragma unroll
  for (int j = 0; j < 8; ++j) {
    float v = W1[(size_t)(krow + j) * 32 + col];
    u16 hi = f2bf(v);
    o[j] = (short)(res ? f2bf(v - bf2f(hi)) : hi);
  }
  *(v8s*)(void*)(dst + (size_t)id * 8) = o;
}

struct P {
  const float* x;
  const u16 *packE, *packC, *packR, *W1f;
  const float *bl, *bc, *br, *b1, *W2, *b2;
  u16 *hxE0, *hxE1, *hxL0, *hxL1, *hxR0, *hxR1;  // packed h-exchange buffers
  float* out;
  u32* bar;
};

// ---- Asb: [32 rows][2048 u16], row stride 4096 B. XOR swizzle on 16B units:
// phys_unit = unit ^ (row & 7). Unit u of row r holds k-range [u*8, u*8+8).
__device__ __forceinline__ v8s ldA(const u16* Asb, int row, int unit) {
  return *(const v8s*)(const void*)(Asb + row * 2048 + ((unit ^ (row & 7)) * 8));
}

// fused stage-barrier, one exchange buffer (encoder / epilogue).
// wave w handles producers w*16+j; q = producer*64 + lane (bijective over 4096).
__device__ __forceinline__ void stage_bar1(u16* Asb, const u32* bar, u32 gen,
                                           int grp, int w, int lane,
                                           const u16* hx, int dstu) {
  pollslice(bar, gen, grp, w, lane);
  v4i t[16];
#pragma unroll
  for (int j = 0; j < 16; ++j) {
    int q = (w * 16 + j) * 64 + lane;
    t[j] = cload128(hx + (size_t)q * 8);
  }
  asm volatile("s_waitcnt vmcnt(0)" ::: "memory");
#pragma unroll
  for (int j = 0; j < 16; ++j) {
    int q = (w * 16 + j) * 64 + lane;
    int sb = q >> 6, rem = q & 63;
    int r = rem >> 1, c8 = rem & 1;
    int u = (dstu + sb * 2 + c8) ^ (r & 7);
    *(v4i*)(void*)(Asb + r * 2048 + u * 8) = t[j];
  }
  __syncthreads();
}

// fused stage-barrier, two exchange buffers (AR phases), 32 loads in flight.
__device__ __forceinline__ void stage_bar2(u16* Asb, const u32* bar, u32 gen,
                                           int grp, int w, int lane,
                                           const u16* hxa, const u16* hxb) {
  pollslice(bar, gen, grp, w, lane);
  v4i a[16], b[16];
#pragma unroll
  for (int j = 0; j < 16; ++j) {
    int q = (w * 16 + j) * 64 + lane;
    a[j] = cload128(hxa + (size_t)q * 8);
  }
#pragma unroll
  for (int j = 0; j < 16; ++j) {
    int q = (w * 16 + j) * 64 + lane;
    b[j] = cload128(hxb + (size_t)q * 8);
  }
  asm volatile("s_waitcnt vmcnt(0)" ::: "memory");
#pragma unroll
  for (int j = 0; j < 16; ++j) {
    int q = (w * 16 + j) * 64 + lane;
    int sb = q >> 6, rem = q & 63;
    int r = rem >> 1, c8 = rem & 1;
    int u = (sb * 2 + c8) ^ (r & 7);
    *(v4i*)(void*)(Asb + r * 2048 + u * 8) = a[j];
  }
#pragma unroll
  for (int j = 0; j < 16; ++j) {
    int q = (w * 16 + j) * 64 + lane;
    int sb = q >> 6, rem = q & 63;
    int r = rem >> 1, c8 = rem & 1;
    int u = (128 + sb * 2 + c8) ^ (r & 7);
    *(v4i*)(void*)(Asb + r * 2048 + u * 8) = b[j];
  }
  __syncthreads();
}

// x(t) -> Xsb (plain loads: x is constant input)
__device__ __forceinline__ void stageX(u16* Xsb, int tid, int m0,
                                       const float* x, int t) {
#pragma unroll
  for (int i = 0; i < 4; ++i) {
    int idx = tid + i * 256;
    int ml = idx >> 5, dw = idx & 31;
    const float* sp = x + ((size_t)(m0 + ml) * NT + t) * NF + dw * 2;
    u32 v = (u32)f2bf(sp[0]) | ((u32)f2bf(sp[1]) << 16);
    *(u32*)(void*)(Xsb + ml * XS + dw * 2) = v;
  }
}

// ---- split-K MFMA: warp w handles chunks j == w (mod 4) for ALL FOUR of the
// block's col-tiles. 8 independent accumulator chains; LDS A-reads /4 vs
// per-warp-tile decomposition. XCH = leading chunks served from Xsb.
template <int NCH, int XCH>
__device__ __forceinline__ void mfmaSK(f32x4 (&acc)[4][2], const u16* Asb,
                                       const u16* Xsb, const u16* pack,
                                       int linesz, int tile0,
                                       int w, int lane, int quad, int l15) {
  const u16* tb0 = pack + (size_t)(tile0 + 0) * linesz;
  const u16* tb1 = pack + (size_t)(tile0 + 1) * linesz;
  const u16* tb2 = pack + (size_t)(tile0 + 2) * linesz;
  const u16* tb3 = pack + (size_t)(tile0 + 3) * linesz;
  for (int j = w; j < NCH; j += 4) {
    v8s a0, a1;
    if (XCH > 0 && j < XCH) {
      a0 = *(const v8s*)(const void*)(Xsb + l15 * XS + j * 32 + quad * 8);
      a1 = *(const v8s*)(const void*)(Xsb + (16 + l15) * XS + j * 32 + quad * 8);
    } else {
      int u = (j - XCH) * 4 + quad;
      a0 = ldA(Asb, l15, u);
      a1 = ldA(Asb, 16 + l15, u);
    }
    size_t bo = (size_t)(j * 64 + lane) * 8;
    v8s b0 = *(const v8s*)(const void*)(tb0 + bo);
    v8s b1 = *(const v8s*)(const void*)(tb1 + bo);
    v8s b2 = *(const v8s*)(const void*)(tb2 + bo);
    v8s b3 = *(const v8s*)(const void*)(tb3 + bo);
    acc[0][0] = __builtin_amdgcn_mfma_f32_16x16x32_bf16(a0, b0, acc[0][0], 0, 0, 0);
    acc[1][0] = __builtin_amdgcn_mfma_f32_16x16x32_bf16(a0, b1, acc[1][0], 0, 0, 0);
    acc[2][0] = __builtin_amdgcn_mfma_f32_16x16x32_bf16(a0, b2, acc[2][0], 0, 0, 0);
    acc[3][0] = __builtin_amdgcn_mfma_f32_16x16x32_bf16(a0, b3, acc[3][0], 0, 0, 0);
    acc[0][1] = __builtin_amdgcn_mfma_f32_16x16x32_bf16(a1, b0, acc[0][1], 0, 0, 0);
    acc[1][1] = __builtin_amdgcn_mfma_f32_16x16x32_bf16(a1, b1, acc[1][1], 0, 0, 0);
    acc[2][1] = __builtin_amdgcn_mfma_f32_16x16x32_bf16(a1, b2, acc[2][1], 0, 0, 0);
    acc[3][1] = __builtin_amdgcn_mfma_f32_16x16x32_bf16(a1, b3, acc[3][1], 0, 0, 0);
  }
}

// gates tail with split-K reduce. Partial-z layout:
//   MFMA C/D: batch row = quad*4+r (+16 for the a1 half), weight col = l15.
//   zb[(wsrc*32 + batch_row) * ZBS + tile*16 + wcol]   (overlaid on Asb; all
//   Asb contents dead post-MFMA). Write banks 2-way, read banks 2-way -> free.
// Ends with the coherent h store; publish() provides drain + sync.
__device__ __forceinline__ void gates_store(float* zb, u16* hpk,
                                            int w, int lane, int quad, int l15,
                                            int wgn, int bid,
                                            const f32x4 (&acc)[4][2],
                                            const float* bias,
                                            float cpair[2], u16* hxout, bool czero) {
  __syncthreads();  // all warps done reading Asb/Xsb before overlay write
#pragma unroll
  for (int tt = 0; tt < 4; ++tt)
#pragma unroll
    for (int rt = 0; rt < 2; ++rt)
#pragma unroll
      for (int r = 0; r < 4; ++r)
        zb[(size_t)(w * 32 + rt * 16 + quad * 4 + r) * ZBS + tt * 16 + l15] =
            acc[tt][rt][r];
  __syncthreads();
  const int tblk = wgn * 4 + w;
#pragma unroll
  for (int rep = 0; rep < 2; ++rep) {
    int pp = lane + rep * 64;
    int ml = pp >> 2;
    int cc = pp & 3;
    int col = tblk * 4 + cc;
    float zg[4];
#pragma unroll
    for (int g = 0; g < 4; ++g) {
      int zc = w * 16 + g * 4 + cc;  // this warp reduces its own tile's cols
      float s = zb[(size_t)(0 * 32 + ml) * ZBS + zc] +
                zb[(size_t)(1 * 32 + ml) * ZBS + zc] +
                zb[(size_t)(2 * 32 + ml) * ZBS + zc] +
                zb[(size_t)(3 * 32 + ml) * ZBS + zc];
      zg[g] = s + bias[g * 1024 + col];
    }
    float cold = czero ? 0.f : cpair[rep];
    float si = 1.f / (1.f + __expf(-zg[0]));
    float sf = 1.f / (1.f + __expf(-zg[1]));
    float so = 1.f / (1.f + __expf(-zg[3]));
    float e2g = __expf(2.f * zg[2]);
    float tg  = (e2g - 1.f) / (e2g + 1.f);
    float cn  = sf * cold + si * tg;
    float e2c = __expf(2.f * cn);
    float tc  = (e2c - 1.f) / (e2c + 1.f);
    cpair[rep] = cn;
    hpk[w * 128 + ml * 4 + cc] = f2bf(so * tc);
  }
  __syncthreads();
  {
    int tid = w * 64 + lane;
    int r = tid >> 3, c2 = tid & 7;
    int wsrc = c2 >> 1;
    u32 v = *(const u32*)(const void*)(hpk + wsrc * 128 + r * 4 + (c2 & 1) * 2);
    cstore32((u32*)(void*)(hxout + (size_t)bid * 512) + r * 8 + c2, v);
  }
}

// In-block dense head from Asb half1 (hr tile): layer1 = MFMA over W1 hi+lo,
// relu via LDS; layer2 scalar fp32. Writes pred (bf16) to Xsb; leader also
// stores fp32 out for `step`.
__device__ __forceinline__ void dense_head(const P& p, const u16* Asb, float* d1s,
                                           u16* Xsb, int tid, int w, int lane,
                                           int quad, int l15, int m0, int step,
                                           bool wout) {
  const int rt = w >> 1, ct = w & 1;
  const int arow = rt * 16 + l15;
  const u16* wf = p.W1f;
  f32x4 acc0 = {0.f, 0.f, 0.f, 0.f}, acc1 = acc0;
#pragma unroll
  for (int k = 0; k < 16; ++k) {
    v8s b0 = *(const v8s*)(const void*)(wf + ((size_t)((2 * k) * 2 + ct) * 64 + lane) * 8);
    v8s a0 = ldA(Asb, arow, 128 + (2 * k) * 4 + quad);
    v8s b1 = *(const v8s*)(const void*)(wf + ((size_t)((2 * k + 1) * 2 + ct) * 64 + lane) * 8);
    v8s a1 = ldA(Asb, arow, 128 + (2 * k + 1) * 4 + quad);
    acc0 = __builtin_amdgcn_mfma_f32_16x16x32_bf16(a0, b0, acc0, 0, 0, 0);
    acc1 = __builtin_amdgcn_mfma_f32_16x16x32_bf16(a1, b1, acc1, 0, 0, 0);
  }
#pragma unroll
  for (int k = 0; k < 16; ++k) {  // residual (lo) part
    v8s b0 = *(const v8s*)(const void*)(wf + ((size_t)(64 + (2 * k) * 2 + ct) * 64 + lane) * 8);
    v8s a0 = ldA(Asb, arow, 128 + (2 * k) * 4 + quad);
    v8s b1 = *(const v8s*)(const void*)(wf + ((size_t)(64 + (2 * k + 1) * 2 + ct) * 64 + lane) * 8);
    v8s a1 = ldA(Asb, arow, 128 + (2 * k + 1) * 4 + quad);
    acc0 = __builtin_amdgcn_mfma_f32_16x16x32_bf16(a0, b0, acc0, 0, 0, 0);
    acc1 = __builtin_amdgcn_mfma_f32_16x16x32_bf16(a1, b1, acc1, 0, 0, 0);
  }
  acc0 += acc1;
  const int col = ct * 16 + l15;
  const float b1c = p.b1[col];
#pragma unroll
  for (int r = 0; r < 4; ++r) {
    int row = rt * 16 + quad * 4 + r;
    d1s[row * 33 + col] = fmaxf(acc0[r] + b1c, 0.f);
  }
  __syncthreads();
  const int r = tid >> 3, cb = (tid & 7) * 8;
  float s2[8];
#pragma unroll
  for (int cc = 0; cc < 8; ++cc) s2[cc] = p.b2[cb + cc];
#pragma unroll
  for (int k = 0; k < 32; ++k) {
    float dv = d1s[r * 33 + k];
    f32x4 w20 = *(const f32x4*)(const void*)(p.W2 + k * 64 + cb);
    f32x4 w21 = *(const f32x4*)(const void*)(p.W2 + k * 64 + cb + 4);
    s2[0] += dv * w20[0]; s2[1] += dv * w20[1];
    s2[2] += dv * w20[2]; s2[3] += dv * w20[3];
    s2[4] += dv * w21[0]; s2[5] += dv * w21[1];
    s2[6] += dv * w21[2]; s2[7] += dv * w21[3];
  }
#pragma unroll
  for (int cc = 0; cc < 8; ++cc) Xsb[r * XS + cb + cc] = f2bf(s2[cc]);
  if (wout) {
    float* po = p.out + ((size_t)(m0 + r) * NOUT + step) * NF + cb;
#pragma unroll
    for (int cc = 0; cc < 8; ++cc) po[cc] = s2[cc];
  }
  __syncthreads();
}

__global__ void __launch_bounds__(256, 1) rnn_persist(P p) {
  __shared__ __align__(16) u16 Asb[32 * 2048];  // 131,072 B (zb overlays start)
  __shared__ __align__(16) u16 Xsb[32 * XS];    //   4,608 B
  __shared__ float d1s[32 * 33];                //   4,224 B
  __shared__ u16 hpack[512];                    //   1,024 B
  float* zb = (float*)(void*)Asb;               // 128*ZBS f32 = 33,792 B

  const int tid = threadIdx.x;
  const int bid = blockIdx.x;
  const int wgn = bid & 63;
  const int mg  = bid >> 6;    // 4 independent groups of 64 blocks
  const int m0  = mg * 32;
  const int w    = tid >> 6;
  const int lane = tid & 63;
  const int quad = lane >> 4;
  const int l15  = lane & 15;
  const int tile0 = wgn * 4;
  const size_t gsl = (size_t)mg * 64 * 512;  // group slice offset in hx (u16)

  float cE2[2] = {0.f, 0.f};
  u32 bno = 0;

  // ---- encoder: 256 steps ----
  stageX(Xsb, tid, m0, p.x, 0);
  for (int t = 0; t < NT; ++t) {
    const u16* hread = ((t & 1) ? p.hxE1 : p.hxE0) + gsl;
    u16* hwrite      = (t & 1) ? p.hxE0 : p.hxE1;
    f32x4 acc[4][2];
#pragma unroll
    for (int a = 0; a < 4; ++a)
#pragma unroll
      for (int b = 0; b < 2; ++b) acc[a][b] = (f32x4){0.f, 0.f, 0.f, 0.f};
    if (t > 0) {
      stage_bar1(Asb, p.bar, bno, mg, w, lane, hread, 0);
      mfmaSK<34, 2>(acc, Asb, Xsb, p.packE, 17408, tile0, w, lane, quad, l15);
    } else {
      __syncthreads();  // covers pre-loop stageX
      mfmaSK<2, 2>(acc, Asb, Xsb, p.packE, 17408, tile0, w, lane, quad, l15);
    }
    gates_store(zb, hpack, w, lane, quad, l15, wgn, bid, acc,
                p.bl, cE2, hwrite, t == 0);
    if (t + 1 < NT) stageX(Xsb, tid, m0, p.x, t + 1);  // prefetch across barrier
    publish(p.bar, ++bno, bid, tid);
  }
  // final encoder h in hxE0 (t=255 odd -> wrote hxE0)

  // ---- autoregressive: 31 steps x 2 phases (dense folded into cellC) ----
  float cL2[2] = {cE2[0], cE2[1]};
  float cR2[2] = {cE2[0], cE2[1]};
  for (int s = 1; s < NOUT; ++s) {
    const u16* hlr = ((s == 1) ? p.hxE0 : ((s & 1) ? p.hxL1 : p.hxL0)) + gsl;
    const u16* hrd = ((s == 1) ? p.hxE0 : ((s & 1) ? p.hxR1 : p.hxR0)) + gsl;
    u16* hlw = (s & 1) ? p.hxL0 : p.hxL1;
    u16* hrw = (s & 1) ? p.hxR0 : p.hxR1;

    // cellC phase: stage [hl(s-1) | hr(s-1)], dense(hr) -> pred/out, cell.
    {
      stage_bar2(Asb, p.bar, bno, mg, w, lane, hlr, hrd);
      dense_head(p, Asb, d1s, Xsb, tid, w, lane, quad, l15, m0, s - 1, wgn == 0);
      f32x4 acc[4][2];
#pragma unroll
      for (int a = 0; a < 4; ++a)
#pragma unroll
        for (int b = 0; b < 2; ++b) acc[a][b] = (f32x4){0.f, 0.f, 0.f, 0.f};
      mfmaSK<34, 2>(acc, Asb, Xsb, p.packC, 17408, tile0, w, lane, quad, l15);
      gates_store(zb, hpack, w, lane, quad, l15, wgn, bid, acc,
                  p.bc, cL2, hlw, false);
    }
    publish(p.bar, ++bno, bid, tid);

    // cellR phase: stage [hl(s) | hr(s-1)] (re-staged: zb overlay dirtied Asb).
    {
      stage_bar2(Asb, p.bar, bno, mg, w, lane, hlw + gsl, hrd);
      f32x4 acc[4][2];
#pragma unroll
      for (int a = 0; a < 4; ++a)
#pragma unroll
        for (int b = 0; b < 2; ++b) acc[a][b] = (f32x4){0.f, 0.f, 0.f, 0.f};
      mfmaSK<64, 0>(acc, Asb, Xsb, p.packR, 32768, tile0, w, lane, quad, l15);
      gates_store(zb, hpack, w, lane, quad, l15, wgn, bid, acc,
                  p.br, cR2, hrw, false);
    }
    publish(p.bar, ++bno, bid, tid);
  }

  // epilogue: out[:,31,:] = dense(hr(31)); leaders only (flag-gated stage).
  if (wgn == 0) {
    stage_bar1(Asb, p.bar, bno, mg, w, lane, p.hxR0 + gsl, 128);  // hr(31)
    dense_head(p, Asb, d1s, Xsb, tid, w, lane, quad, l15, m0, NOUT - 1, true);
  }
}

extern "C" void kernel_launch(void* const* d_in, const int* in_sizes, int n_in,
                              void* d_out, int out_size, void* d_ws, size_t ws_size,
                              hipStream_t stream) {
  const float* x  = (const float*)d_in[0];
  const float* Wl = (const float*)d_in[1];
  const float* Rl = (const float*)d_in[2];
  const float* bl = (const float*)d_in[3];
  const float* Wc = (const float*)d_in[4];
  const float* Rc = (const float*)d_in[5];
  const float* bc = (const float*)d_in[6];
  const float* Wr = (const float*)d_in[7];
  const float* Rr = (const float*)d_in[8];
  const float* br = (const float*)d_in[9];
  const float* W1 = (const float*)d_in[10];
  const float* b1 = (const float*)d_in[11];
  const float* W2 = (const float*)d_in[12];
  const float* b2 = (const float*)d_in[13];

  char* ws = (char*)d_ws;
  size_t off = 0;
  auto alloc = [&](size_t bytes) -> void* {
    void* r = ws + off;
    off += (bytes + 255) & ~(size_t)255;
    return r;
  };
  const size_t szPackE = (size_t)256 * 17408 * 2;  // 8,912,896
  const size_t szPackR = (size_t)256 * 32768 * 2;  // 16,777,216
  const size_t szHx    = (size_t)NBLK * 512 * 2;   // 262,144
  u16* packE = (u16*)alloc(szPackE);
  u16* packC = (u16*)alloc(szPackE);
  u16* packR = (u16*)alloc(szPackR);
  u16* W1f   = (u16*)alloc((size_t)128 * 64 * 8 * 2);  // 131,072
  u16* hxE0 = (u16*)alloc(szHx);
  u16* hxE1 = (u16*)alloc(szHx);
  u16* hxL0 = (u16*)alloc(szHx);
  u16* hxL1 = (u16*)alloc(szHx);
  u16* hxR0 = (u16*)alloc(szHx);
  u16* hxR1 = (u16*)alloc(szHx);
  u32* bar = (u32*)alloc(2 * NBLK * FPAD * 4);

  init_bar<<<dim3(64), dim3(256), 0, stream>>>(bar);
  pack_weights<<<dim3(128 * 17), dim3(256), 0, stream>>>(Wl, Rl, 64, 17, packE);
  pack_weights<<<dim3(128 * 17), dim3(256), 0, stream>>>(Wc, Rc, 64, 17, packC);
  pack_weights<<<dim3(128 * 32), dim3(256), 0, stream>>>(Wr, Rr, 1024, 32, packR);
  pack_w1<<<dim3(32), dim3(256), 0, stream>>>(W1, W1f);

  static P p;
  p.x = x;
  p.packE = packE; p.packC = packC; p.packR = packR; p.W1f = W1f;
  p.bl = bl; p.bc = bc; p.br = br;
  p.b1 = b1; p.W2 = W2; p.b2 = b2;
  p.hxE0 = hxE0; p.hxE1 = hxE1;
  p.hxL0 = hxL0; p.hxL1 = hxL1;
  p.hxR0 = hxR0; p.hxR1 = hxR1;
  p.out = (float*)d_out;
  p.bar = bar;

  rnn_persist<<<dim3(NBLK), dim3(256), 0, stream>>>(p);
}

// Round 8
// 2711.303 us; speedup vs baseline: 1.8810x; 1.1116x over previous
//
#include <hip/hip_runtime.h>

typedef unsigned short u16;
typedef unsigned int u32;
typedef unsigned long long u64;
typedef short v8s __attribute__((ext_vector_type(8)));
typedef int v4i __attribute__((ext_vector_type(4)));
typedef float f32x4 __attribute__((ext_vector_type(4)));

#define NB 128
#define NU 1024
#define NF 64
#define NT 256
#define NOUT 32
#define NBLK 512    // 2 blocks per CU: TLP hides barrier/gather latency
#define XS 72       // LDS X row stride in u16
#define FPAD 32     // u32 per barrier flag line (128 B)
#define ZBS 66      // zb row stride (f32)

__device__ __forceinline__ u16 f2bf(float f) {
  union { float f; u32 u; } v; v.f = f;
  u32 x = v.u;
  return (u16)((x + 0x7fffu + ((x >> 16) & 1u)) >> 16);
}
__device__ __forceinline__ float bf2f(u16 u) {
  union { u32 u; float f; } v; v.u = ((u32)u) << 16;
  return v.f;
}

__device__ __forceinline__ void cstore32(u32* p, u32 v) {
  __hip_atomic_store(p, v, __ATOMIC_RELAXED, __HIP_MEMORY_SCOPE_AGENT);
}
// 16B coherent load (MALL point); valid after s_waitcnt vmcnt(0).
__device__ __forceinline__ v4i cload128(const void* p) {
  v4i r;
  asm volatile("global_load_dwordx4 %0, %1, off sc0 sc1" : "=v"(r) : "v"(p) : "memory");
  return r;
}

// ---- fused stage-barrier protocol (r7-proven) ----
__device__ __forceinline__ void publish(u32* bar, u32 gen, int bid, int tid) {
  asm volatile("s_waitcnt vmcnt(0)" ::: "memory");
  __syncthreads();
  if (tid == 0)
    __hip_atomic_store(&bar[bid * FPAD], gen, __ATOMIC_RELAXED, __HIP_MEMORY_SCOPE_AGENT);
}

__device__ __forceinline__ void pollslice(const u32* bar, u32 gen, int grp,
                                          int w, int lane) {
  const u32* fl = bar + (size_t)(grp * 64 + w * 16 + (lane & 15)) * FPAD;
  bool ok = (lane >= 16);
  u32 spin = 0;
  for (;;) {
    if (!ok)
      ok = __hip_atomic_load(fl, __ATOMIC_RELAXED, __HIP_MEMORY_SCOPE_AGENT) >= gen;
    if (__all(ok)) break;
    __builtin_amdgcn_s_sleep(1);
    if (++spin > 4000000u) break;  // escape hatch
  }
}

__global__ void init_bar(u32* bar) {
  int i = blockIdx.x * 256 + threadIdx.x;
  if (i < NBLK * FPAD) bar[i] = 0;
}

// Pack [top(ktop x 4096); R(1024 x 4096)] into MFMA-B-fragment-major bf16 with
// gate-permuted columns: z' col (t*16 + q*4 + c) <- orig col (q*1024 + t*4 + c).
__global__ void pack_weights(const float* __restrict__ top, const float* __restrict__ R,
                             int ktop, int nchunk, u16* __restrict__ dst) {
  int line = blockIdx.x * 256 + threadIdx.x;
  int l = line & 63;
  int rest = line >> 6;
  int s = rest & 1; rest >>= 1;
  int kk = rest % nchunk;
  int t  = rest / nchunk;
  if (t >= 256) return;
  int kbase = kk * 64 + s * 32 + (l >> 4) * 8;
  int col = ((l >> 2) & 3) * 1024 + t * 4 + (l & 3);
  v8s o;
#pragma unroll
  for (int j = 0; j < 8; ++j) {
    int k = kbase + j;
    float v = (k < ktop) ? top[(size_t)k * 4096 + col]
                         : R[(size_t)(k - ktop) * 4096 + col];
    o[j] = (short)f2bf(v);
  }
  *(v8s*)(void*)(dst + (size_t)line * 8) = o;
}

// W1 (1024x32) as bf16 hi (lines 0..63) + residual lo (64..127), fragment-major.
__global__ void pack_w1(const float* __restrict__ W1, u16* __restrict__ dst) {
  int id = blockIdx.x * 256 + threadIdx.x;
  int lane = id & 63;
  int line = id >> 6;
  int res = line >> 6;
  int cl = line & 63;
  int c = cl >> 1, nt = cl & 1;
  int krow = c * 32 + ((lane >> 4) * 8);
  int col = nt * 16 + (lane & 15);
  v8s o;
#pragma unroll
  for (int j = 0; j < 8; ++j) {
    float v = W1[(size_t)(krow + j) * 32 + col];
    u16 hi = f2bf(v);
    o[j] = (short)(res ? f2bf(v - bf2f(hi)) : hi);
  }
  *(v8s*)(void*)(dst + (size_t)id * 8) = o;
}

struct P {
  const float* x;
  const u16 *packE, *packC, *packR, *W1f;
  const float *bl, *bc, *br, *b1, *W2, *b2;
  u16 *hxE0, *hxE1, *hxL0, *hxL1, *hxR0, *hxR1;  // packed h-exchange
  float* out;
  u32* bar;
};

// Asb: [16 rows][2048 u16]; XOR swizzle on 16B units: phys = unit ^ (row & 7).
__device__ __forceinline__ v8s ldA(const u16* Asb, int row, int unit) {
  return *(const v8s*)(const void*)(Asb + row * 2048 + ((unit ^ (row & 7)) * 8));
}

// h-exchange: block b's tile at hx + b*256 u16, [16 rows][16 cols] row-major.
// Producer p owns col-units p*2 + (q&1); per-wave slice = producers w*16..w*16+15.
__device__ __forceinline__ void stage_bar1(u16* Asb, const u32* bar, u32 gen,
                                           int grp, int w, int lane,
                                           const u16* hx, int dstu) {
  pollslice(bar, gen, grp, w, lane);
  v4i t[8];
#pragma unroll
  for (int j = 0; j < 8; ++j) {
    int ul = j * 64 + lane;
    int pl = ul >> 5, q = ul & 31;
    t[j] = cload128(hx + (size_t)((w * 16 + pl) * 32 + q) * 8);
  }
  asm volatile("s_waitcnt vmcnt(0)" ::: "memory");
#pragma unroll
  for (int j = 0; j < 8; ++j) {
    int ul = j * 64 + lane;
    int pl = ul >> 5, q = ul & 31;
    int r = q >> 1, c8 = q & 1;
    int u = (dstu + (w * 16 + pl) * 2 + c8) ^ (r & 7);
    *(v4i*)(void*)(Asb + r * 2048 + u * 8) = t[j];
  }
  __syncthreads();
}

__device__ __forceinline__ void stage_bar2(u16* Asb, const u32* bar, u32 gen,
                                           int grp, int w, int lane,
                                           const u16* hxa, const u16* hxb) {
  pollslice(bar, gen, grp, w, lane);
  v4i a[8], b[8];
#pragma unroll
  for (int j = 0; j < 8; ++j) {
    int ul = j * 64 + lane;
    int pl = ul >> 5, q = ul & 31;
    a[j] = cload128(hxa + (size_t)((w * 16 + pl) * 32 + q) * 8);
  }
#pragma unroll
  for (int j = 0; j < 8; ++j) {
    int ul = j * 64 + lane;
    int pl = ul >> 5, q = ul & 31;
    b[j] = cload128(hxb + (size_t)((w * 16 + pl) * 32 + q) * 8);
  }
  asm volatile("s_waitcnt vmcnt(0)" ::: "memory");
#pragma unroll
  for (int j = 0; j < 8; ++j) {
    int ul = j * 64 + lane;
    int pl = ul >> 5, q = ul & 31;
    int r = q >> 1, c8 = q & 1;
    int u = ((w * 16 + pl) * 2 + c8) ^ (r & 7);
    *(v4i*)(void*)(Asb + r * 2048 + u * 8) = a[j];
  }
#pragma unroll
  for (int j = 0; j < 8; ++j) {
    int ul = j * 64 + lane;
    int pl = ul >> 5, q = ul & 31;
    int r = q >> 1, c8 = q & 1;
    int u = (128 + (w * 16 + pl) * 2 + c8) ^ (r & 7);
    *(v4i*)(void*)(Asb + r * 2048 + u * 8) = b[j];
  }
  __syncthreads();
}

// x(t) -> Xsb: 16 rows x 64 cols (plain loads, constant input)
__device__ __forceinline__ void stageX(u16* Xsb, int tid, int m0,
                                       const float* x, int t) {
#pragma unroll
  for (int i = 0; i < 2; ++i) {
    int idx = tid + i * 256;
    int ml = idx >> 5, dw = idx & 31;
    const float* sp = x + ((size_t)(m0 + ml) * NT + t) * NF + dw * 2;
    u32 v = (u32)f2bf(sp[0]) | ((u32)f2bf(sp[1]) << 16);
    *(u32*)(void*)(Xsb + ml * XS + dw * 2) = v;
  }
}

// split-K MFMA (M=16): warp w handles chunks j == w (mod 4) for all 4 col-tiles.
template <int NCH, int XCH>
__device__ __forceinline__ void mfmaSK(f32x4 (&acc)[4], const u16* Asb,
                                       const u16* Xsb, const u16* pack,
                                       int linesz, int tile0,
                                       int w, int lane, int quad, int l15) {
  const u16* tb0 = pack + (size_t)(tile0 + 0) * linesz;
  const u16* tb1 = pack + (size_t)(tile0 + 1) * linesz;
  const u16* tb2 = pack + (size_t)(tile0 + 2) * linesz;
  const u16* tb3 = pack + (size_t)(tile0 + 3) * linesz;
  for (int j = w; j < NCH; j += 4) {
    v8s a0;
    if (XCH > 0 && j < XCH) {
      a0 = *(const v8s*)(const void*)(Xsb + l15 * XS + j * 32 + quad * 8);
    } else {
      a0 = ldA(Asb, l15, (j - XCH) * 4 + quad);
    }
    size_t bo = (size_t)(j * 64 + lane) * 8;
    v8s b0 = *(const v8s*)(const void*)(tb0 + bo);
    v8s b1 = *(const v8s*)(const void*)(tb1 + bo);
    v8s b2 = *(const v8s*)(const void*)(tb2 + bo);
    v8s b3 = *(const v8s*)(const void*)(tb3 + bo);
    acc[0] = __builtin_amdgcn_mfma_f32_16x16x32_bf16(a0, b0, acc[0], 0, 0, 0);
    acc[1] = __builtin_amdgcn_mfma_f32_16x16x32_bf16(a0, b1, acc[1], 0, 0, 0);
    acc[2] = __builtin_amdgcn_mfma_f32_16x16x32_bf16(a0, b2, acc[2], 0, 0, 0);
    acc[3] = __builtin_amdgcn_mfma_f32_16x16x32_bf16(a0, b3, acc[3], 0, 0, 0);
  }
}

// gates tail with split-K reduce (M=16). MFMA C/D: row = quad*4+r, col = l15.
// zb[(wsrc*16 + row)*ZBS + tile*16 + col] overlaid on Asb (dead post-MFMA).
// One output per thread: tid -> (row = tid>>4, hcol = tid&15); c in 1 register.
__device__ __forceinline__ void gates_store(float* zb, u16* hpk,
                                            int w, int lane, int quad, int l15,
                                            int wgn, int bid, int tid,
                                            const f32x4 (&acc)[4],
                                            const float* bias,
                                            float& creg, u16* hxout, bool czero) {
  __syncthreads();  // all warps done reading Asb/Xsb before overlay write
#pragma unroll
  for (int tt = 0; tt < 4; ++tt)
#pragma unroll
    for (int r = 0; r < 4; ++r)
      zb[(size_t)(w * 16 + quad * 4 + r) * ZBS + tt * 16 + l15] = acc[tt][r];
  __syncthreads();
  {
    int r = tid >> 4, hc = tid & 15;
    int tt = hc >> 2, cc = hc & 3;
    int col = wgn * 16 + hc;
    float zg[4];
#pragma unroll
    for (int g = 0; g < 4; ++g) {
      int zc = tt * 16 + g * 4 + cc;
      float s = zb[(size_t)(0 * 16 + r) * ZBS + zc] +
                zb[(size_t)(1 * 16 + r) * ZBS + zc] +
                zb[(size_t)(2 * 16 + r) * ZBS + zc] +
                zb[(size_t)(3 * 16 + r) * ZBS + zc];
      zg[g] = s + bias[g * 1024 + col];
    }
    float cold = czero ? 0.f : creg;
    float si = 1.f / (1.f + __expf(-zg[0]));
    float sf = 1.f / (1.f + __expf(-zg[1]));
    float so = 1.f / (1.f + __expf(-zg[3]));
    float e2g = __expf(2.f * zg[2]);
    float tg  = (e2g - 1.f) / (e2g + 1.f);
    float cn  = sf * cold + si * tg;
    float e2c = __expf(2.f * cn);
    float tc  = (e2c - 1.f) / (e2c + 1.f);
    creg = cn;
    hpk[r * 16 + hc] = f2bf(so * tc);
  }
  __syncthreads();
  if (tid < 128) {
    int rr = tid >> 3, c2 = tid & 7;
    u32 v = *(const u32*)(const void*)(hpk + rr * 16 + c2 * 2);
    cstore32((u32*)(void*)(hxout + (size_t)bid * 256) + rr * 8 + c2, v);
  }
}

// dense head (M=16) from Asb half1 (hr tile, units 128+). Warp w: col-tile
// nt=w&1, k-parity kp=w>>1 (hi+lo W1 both). Partials summed (+b1, relu) in
// layer-2 pass. pred (bf16) -> Xsb rows 0..15; fp32 out if wout.
__device__ __forceinline__ void dense_head(const P& p, const u16* Asb, float* d1s,
                                           u16* Xsb, int tid, int w, int lane,
                                           int quad, int l15, int m0, int step,
                                           bool wout) {
  const int nt = w & 1, kp = w >> 1;
  const u16* wf = p.W1f;
  f32x4 aH = {0.f, 0.f, 0.f, 0.f}, aL = aH;
#pragma unroll
  for (int k = 0; k < 16; ++k) {
    int c = kp + 2 * k;
    v8s a  = ldA(Asb, l15, 128 + c * 4 + quad);
    v8s bh = *(const v8s*)(const void*)(wf + ((size_t)(c * 2 + nt) * 64 + lane) * 8);
    v8s bl = *(const v8s*)(const void*)(wf + ((size_t)(64 + c * 2 + nt) * 64 + lane) * 8);
    aH = __builtin_amdgcn_mfma_f32_16x16x32_bf16(a, bh, aH, 0, 0, 0);
    aL = __builtin_amdgcn_mfma_f32_16x16x32_bf16(a, bl, aL, 0, 0, 0);
  }
  aH += aL;
#pragma unroll
  for (int r = 0; r < 4; ++r)
    d1s[kp * 528 + (quad * 4 + r) * 33 + nt * 16 + l15] = aH[r];
  __syncthreads();
  {
    int r = tid >> 4, cb = (tid & 15) * 4;
    float s2[4];
#pragma unroll
    for (int j = 0; j < 4; ++j) s2[j] = p.b2[cb + j];
#pragma unroll
    for (int k = 0; k < 32; ++k) {
      float dv = fmaxf(d1s[r * 33 + k] + d1s[528 + r * 33 + k] + p.b1[k], 0.f);
      f32x4 w2 = *(const f32x4*)(const void*)(p.W2 + k * 64 + cb);
      s2[0] += dv * w2[0]; s2[1] += dv * w2[1];
      s2[2] += dv * w2[2]; s2[3] += dv * w2[3];
    }
#pragma unroll
    for (int j = 0; j < 4; ++j) Xsb[r * XS + cb + j] = f2bf(s2[j]);
    if (wout) {
      float* po = p.out + ((size_t)(m0 + r) * NOUT + step) * NF + cb;
#pragma unroll
      for (int j = 0; j < 4; ++j) po[j] = s2[j];
    }
  }
  __syncthreads();
}

__global__ void __launch_bounds__(256, 2) rnn_persist(P p) {
  __shared__ __align__(16) u16 Asb[16 * 2048];  // 65,536 B (zb overlays start)
  __shared__ __align__(16) u16 Xsb[16 * XS];    //  2,304 B
  __shared__ float d1s[2 * 16 * 33];            //  4,224 B
  __shared__ u16 hpack[256];                    //    512 B
  float* zb = (float*)(void*)Asb;               // 64*ZBS f32 = 16,896 B

  const int tid = threadIdx.x;
  const int bid = blockIdx.x;
  const int wgn = bid & 63;
  const int grp = bid >> 6;    // 8 independent groups of 64 blocks, 16 rows each
  const int m0  = grp * 16;
  const int w    = tid >> 6;
  const int lane = tid & 63;
  const int quad = lane >> 4;
  const int l15  = lane & 15;
  const int tile0 = wgn * 4;
  const size_t gsl = (size_t)grp * 64 * 256;  // group slice offset in hx (u16)

  float cE = 0.f;
  u32 bno = 0;

  // ---- encoder: 256 steps ----
  stageX(Xsb, tid, m0, p.x, 0);
  for (int t = 0; t < NT; ++t) {
    const u16* hread = ((t & 1) ? p.hxE1 : p.hxE0) + gsl;
    u16* hwrite      = (t & 1) ? p.hxE0 : p.hxE1;
    f32x4 acc[4];
#pragma unroll
    for (int a = 0; a < 4; ++a) acc[a] = (f32x4){0.f, 0.f, 0.f, 0.f};
    if (t > 0) {
      stage_bar1(Asb, p.bar, bno, grp, w, lane, hread, 0);
      mfmaSK<34, 2>(acc, Asb, Xsb, p.packE, 17408, tile0, w, lane, quad, l15);
    } else {
      __syncthreads();  // covers pre-loop stageX
      mfmaSK<2, 2>(acc, Asb, Xsb, p.packE, 17408, tile0, w, lane, quad, l15);
    }
    gates_store(zb, hpack, w, lane, quad, l15, wgn, bid, tid, acc,
                p.bl, cE, hwrite, t == 0);
    if (t + 1 < NT) stageX(Xsb, tid, m0, p.x, t + 1);  // prefetch across barrier
    publish(p.bar, ++bno, bid, tid);
  }
  // final encoder h in hxE0 (t=255 odd)

  // ---- autoregressive: 31 steps x 2 phases ----
  float cL = cE;
  float cR = cE;
  for (int s = 1; s < NOUT; ++s) {
    const u16* hlr = ((s == 1) ? p.hxE0 : ((s & 1) ? p.hxL1 : p.hxL0)) + gsl;
    const u16* hrd = ((s == 1) ? p.hxE0 : ((s & 1) ? p.hxR1 : p.hxR0)) + gsl;
    u16* hlw = (s & 1) ? p.hxL0 : p.hxL1;
    u16* hrw = (s & 1) ? p.hxR0 : p.hxR1;

    // cellC: stage [hl(s-1) | hr(s-1)], dense(hr) -> pred/out, then cell.
    {
      stage_bar2(Asb, p.bar, bno, grp, w, lane, hlr, hrd);
      dense_head(p, Asb, d1s, Xsb, tid, w, lane, quad, l15, m0, s - 1, wgn == 0);
      f32x4 acc[4];
#pragma unroll
      for (int a = 0; a < 4; ++a) acc[a] = (f32x4){0.f, 0.f, 0.f, 0.f};
      mfmaSK<34, 2>(acc, Asb, Xsb, p.packC, 17408, tile0, w, lane, quad, l15);
      gates_store(zb, hpack, w, lane, quad, l15, wgn, bid, tid, acc,
                  p.bc, cL, hlw, false);
    }
    publish(p.bar, ++bno, bid, tid);

    // cellR: stage [hl(s) | hr(s-1)] (re-staged: zb overlay dirtied Asb).
    {
      stage_bar2(Asb, p.bar, bno, grp, w, lane, hlw + gsl, hrd);
      f32x4 acc[4];
#pragma unroll
      for (int a = 0; a < 4; ++a) acc[a] = (f32x4){0.f, 0.f, 0.f, 0.f};
      mfmaSK<64, 0>(acc, Asb, Xsb, p.packR, 32768, tile0, w, lane, quad, l15);
      gates_store(zb, hpack, w, lane, quad, l15, wgn, bid, tid, acc,
                  p.br, cR, hrw, false);
    }
    publish(p.bar, ++bno, bid, tid);
  }

  // epilogue: out[:,31,:] = dense(hr(31)); leaders only (flag-gated stage).
  if (wgn == 0) {
    stage_bar1(Asb, p.bar, bno, grp, w, lane, p.hxR0 + gsl, 128);  // hr(31)
    dense_head(p, Asb, d1s, Xsb, tid, w, lane, quad, l15, m0, NOUT - 1, true);
  }
}

extern "C" void kernel_launch(void* const* d_in, const int* in_sizes, int n_in,
                              void* d_out, int out_size, void* d_ws, size_t ws_size,
                              hipStream_t stream) {
  const float* x  = (const float*)d_in[0];
  const float* Wl = (const float*)d_in[1];
  const float* Rl = (const float*)d_in[2];
  const float* bl = (const float*)d_in[3];
  const float* Wc = (const float*)d_in[4];
  const float* Rc = (const float*)d_in[5];
  const float* bc = (const float*)d_in[6];
  const float* Wr = (const float*)d_in[7];
  const float* Rr = (const float*)d_in[8];
  const float* br = (const float*)d_in[9];
  const float* W1 = (const float*)d_in[10];
  const float* b1 = (const float*)d_in[11];
  const float* W2 = (const float*)d_in[12];
  const float* b2 = (const float*)d_in[13];

  char* ws = (char*)d_ws;
  size_t off = 0;
  auto alloc = [&](size_t bytes) -> void* {
    void* r = ws + off;
    off += (bytes + 255) & ~(size_t)255;
    return r;
  };
  const size_t szPackE = (size_t)256 * 17408 * 2;  // 8,912,896
  const size_t szPackR = (size_t)256 * 32768 * 2;  // 16,777,216
  const size_t szHx    = (size_t)NBLK * 256 * 2;   // 262,144
  u16* packE = (u16*)alloc(szPackE);
  u16* packC = (u16*)alloc(szPackE);
  u16* packR = (u16*)alloc(szPackR);
  u16* W1f   = (u16*)alloc((size_t)128 * 64 * 8 * 2);  // 131,072
  u16* hxE0 = (u16*)alloc(szHx);
  u16* hxE1 = (u16*)alloc(szHx);
  u16* hxL0 = (u16*)alloc(szHx);
  u16* hxL1 = (u16*)alloc(szHx);
  u16* hxR0 = (u16*)alloc(szHx);
  u16* hxR1 = (u16*)alloc(szHx);
  u32* bar = (u32*)alloc((size_t)NBLK * FPAD * 4);

  init_bar<<<dim3(64), dim3(256), 0, stream>>>(bar);
  pack_weights<<<dim3(128 * 17), dim3(256), 0, stream>>>(Wl, Rl, 64, 17, packE);
  pack_weights<<<dim3(128 * 17), dim3(256), 0, stream>>>(Wc, Rc, 64, 17, packC);
  pack_weights<<<dim3(128 * 32), dim3(256), 0, stream>>>(Wr, Rr, 1024, 32, packR);
  pack_w1<<<dim3(32), dim3(256), 0, stream>>>(W1, W1f);

  static P p;
  p.x = x;
  p.packE = packE; p.packC = packC; p.packR = packR; p.W1f = W1f;
  p.bl = bl; p.bc = bc; p.br = br;
  p.b1 = b1; p.W2 = W2; p.b2 = b2;
  p.hxE0 = hxE0; p.hxE1 = hxE1;
  p.hxL0 = hxL0; p.hxL1 = hxL1;
  p.hxR0 = hxR0; p.hxR1 = hxR1;
  p.out = (float*)d_out;
  p.bar = bar;

  rnn_persist<<<dim3(NBLK), dim3(256), 0, stream>>>(p);
}